// Round 9
// baseline (236.607 us; speedup 1.0000x reference)
//
#include <hip/hip_runtime.h>
#include <hip/hip_fp16.h>
#include <math.h>

// Problem constants
#define BB 2
#define HH 64
#define WW 64
#define DD 64
#define PH 62          // (H-K)/stride+1
#define CC 3844        // PH*PH
#define CCP 3968       // CC padded to mult of 128
#define PL 576         // K*K*D
#define PLP 640        // PL padded to mult of 128
#define TP 8
#define LAM 10.0f

typedef _Float16 f16;
typedef __attribute__((ext_vector_type(8))) _Float16 half8;
typedef __attribute__((ext_vector_type(4))) float f32x4;

// ======================= FAST PATH (MFMA) =======================
// ws layout (bytes) — bg f32 region retained for fallback-compat but unused:
//  bg   f32 [2][4096][64]       @ 0           2,097,152   (UNUSED in fast path)
//  fgp  f16 [2][4356][64]       @ 2,097,152   1,115,136   (66x66 padded fg image)
//  bgf  f16 [2][4288][64]       @ 3,212,288   1,097,728   (bg pixels + zero page)
//  P1T  f16 [2][640][3968]      @ 4,310,016   10,158,080
//  CS   f16 [2][4096][3968]     @ 14,468,096  65,011,712
//  N2   f16 [2][4096][640]      @ 79,479,808  10,485,760
//  k1d  f32 [2][3968]           @ 89,965,568  31,744
//  sden f32 [2][4096]           @ 89,997,312  32,768
#define REQ_FAST 90030080ULL

__device__ __forceinline__ void gld16(const void* g, void* l) {
  __builtin_amdgcn_global_load_lds((const __attribute__((address_space(1))) void*)g,
                                   (__attribute__((address_space(3))) void*)l, 16, 0, 0);
}

// merged prep: bgf (masked f16 + zero page), fgp (padded fg f16),
// P1T (im2col^T from bg_in*mask), k1d (patch norms) — all independent ranges.
__global__ __launch_bounds__(256) void k_preall(
    const float* __restrict__ bg_in, const float* __restrict__ fg,
    const float* __restrict__ mask, f16* __restrict__ bgf,
    f16* __restrict__ fgp, f16* __restrict__ P1T, float* __restrict__ k1d) {
  const int NBG = BB * 4288 * 64;
  const int NFG = BB * 4356 * 64;
  const int NP1T = BB * PLP * CCP;
  int idx = blockIdx.x * 256 + threadIdx.x;
  if (idx < NBG) {
    int ch = idx & 63;
    int pix = (idx >> 6) % 4288;
    int b = idx / (4288 * 64);
    f16 v = (f16)0.f;
    if (pix < 4096) {
      size_t src = ((size_t)b * 4096 + pix) * 64 + ch;
      v = (f16)(bg_in[src] * mask[((size_t)b * 4096 + pix) * 64]);
    }
    bgf[idx] = v;
  } else if (idx < NBG + NFG) {
    int i2 = idx - NBG;
    int ch = i2 & 63;
    int pix = (i2 >> 6) % 4356;
    int b = i2 / (4356 * 64);
    int yy = pix / 66, xx = pix - 66 * yy;
    float v = 0.f;
    if (yy >= 1 && yy <= 64 && xx >= 1 && xx <= 64)
      v = fg[(((size_t)b * 64 + (yy - 1)) * 64 + (xx - 1)) * 64 + ch];
    fgp[i2] = (f16)v;
  } else if (idx < NBG + NFG + NP1T) {
    int i3 = idx - (NBG + NFG);
    int c = i3 % CCP;
    int rest = i3 / CCP;
    int r = rest % PLP, b = rest / PLP;
    float v = 0.f;
    if (r < PL && c < CC) {
      int ci = c / PH, cj = c - ci * PH;
      int kk = r >> 6, ch = r & 63;
      int ki = kk / 3, kj = kk - 3 * ki;
      int pix = (ci + ki) * WW + cj + kj;
      v = bg_in[((size_t)b * 4096 + pix) * 64 + ch] *
          mask[((size_t)b * 4096 + pix) * 64];
    }
    P1T[i3] = (f16)v;
  } else if (idx < NBG + NFG + NP1T + BB * CC) {
    int i4 = idx - (NBG + NFG + NP1T);
    int b = i4 / CC, c = i4 - b * CC;
    int ci = c / PH, cj = c - ci * PH;
    float s = 0.f;
    for (int ki = 0; ki < 3; ++ki)
      for (int kj = 0; kj < 3; ++kj) {
        int pix = (ci + ki) * WW + cj + kj;
        float m = mask[((size_t)b * 4096 + pix) * 64];
        float m2 = m * m;
        const float4* p = (const float4*)(bg_in + ((size_t)b * 4096 + pix) * 64);
#pragma unroll
        for (int q = 0; q < 16; ++q) {
          float4 v = p[q];
          s += m2 * (v.x * v.x + v.y * v.y + v.z * v.z + v.w * v.w);
        }
      }
    k1d[(size_t)b * CCP + c] = s;
  }
}

// GEMM1: CS[pos][c] = dot(fg patch pos, bg patch c). A,B staged directly from
// padded f16 images (BK=64 == one (ki,kj) tap). 128x128 tile, 8 waves (2x4,
// wave tile 64x32), 512 threads, dbuf LDS 64 KB -> 2 blocks/CU = 16 waves/CU.
__global__ __launch_bounds__(512) void k_gemm1(
    const f16* __restrict__ fgp, const f16* __restrict__ bgf,
    f16* __restrict__ CS) {
  __shared__ f16 tA[2][128 * 64];
  __shared__ f16 tB[2][128 * 64];
  const int tid = threadIdx.x;
  const int l = tid & 63, w = tid >> 6;  // w in [0,8)
  const int b = blockIdx.z;
  const int m0 = blockIdx.y * 128, n0 = blockIdx.x * 128;
  const f16* fgB = fgp + (size_t)b * (4356 * 64);
  const f16* bgB = bgf + (size_t)b * (4288 * 64);

  int pixA[2], chSA[2], aCh[2];
#pragma unroll
  for (int i = 0; i < 2; ++i) {
    aCh[i] = w * 2 + i;
    int li = aCh[i] * 64 + l;
    int r = li >> 3;
    int j = (li & 7) ^ (r & 7);
    chSA[i] = j * 8;
    int pos = m0 + r;
    pixA[i] = (pos >> 6) * 66 + (pos & 63);
  }
  int pixB[2], chSB[2], bCh[2];
#pragma unroll
  for (int i = 0; i < 2; ++i) {
    bCh[i] = w * 2 + i;
    int li = bCh[i] * 64 + l;
    int r = li >> 3;
    int j = (li & 7) ^ (r & 7);
    chSB[i] = j * 8;
    int c = n0 + r;
    if (c < CC) {
      int ci = c / 62;
      pixB[i] = ci * 64 + (c - 62 * ci);
    } else {
      pixB[i] = 4096;  // zero page
    }
  }

  const int wm = (w >> 2) * 64, wn = (w & 3) * 32;
  const int lr = l & 15, lk = l >> 4;
  const int xr = (lr & 7) << 4;

  f32x4 acc[4][2];
#pragma unroll
  for (int mi = 0; mi < 4; ++mi)
#pragma unroll
    for (int ni = 0; ni < 2; ++ni) acc[mi][ni] = (f32x4){0.f, 0.f, 0.f, 0.f};

#pragma unroll
  for (int i = 0; i < 2; ++i) {
    gld16(fgB + (size_t)pixA[i] * 64 + chSA[i], (char*)tA[0] + aCh[i] * 1024);
    gld16(bgB + (size_t)pixB[i] * 64 + chSB[i], (char*)tB[0] + bCh[i] * 1024);
  }
  asm volatile("s_waitcnt vmcnt(0)" ::: "memory");
  __syncthreads();

#pragma unroll 1
  for (int t = 0; t < 9; ++t) {
    const int cur = t & 1;
    if (t + 1 < 9) {
      const int tn = t + 1;
      const int ki = tn / 3, kj = tn - 3 * ki;
      const int offA = ki * 66 + kj, offB = ki * 64 + kj;
#pragma unroll
      for (int i = 0; i < 2; ++i) {
        gld16(fgB + (size_t)(pixA[i] + offA) * 64 + chSA[i],
              (char*)tA[cur ^ 1] + aCh[i] * 1024);
        gld16(bgB + (size_t)(pixB[i] + offB) * 64 + chSB[i],
              (char*)tB[cur ^ 1] + bCh[i] * 1024);
      }
    }
#pragma unroll
    for (int kk = 0; kk < 2; ++kk) {
      half8 av[4], bv[2];
      const int cb = lk * 16 + kk * 64;
#pragma unroll
      for (int mi = 0; mi < 4; ++mi) {
        int r = wm + mi * 16 + lr;
        av[mi] = *(const half8*)((const char*)tA[cur] + r * 128 + (cb ^ xr));
      }
#pragma unroll
      for (int ni = 0; ni < 2; ++ni) {
        int r = wn + ni * 16 + lr;
        bv[ni] = *(const half8*)((const char*)tB[cur] + r * 128 + (cb ^ xr));
      }
#pragma unroll
      for (int mi = 0; mi < 4; ++mi)
#pragma unroll
        for (int ni = 0; ni < 2; ++ni)
          acc[mi][ni] = __builtin_amdgcn_mfma_f32_16x16x32_f16(
              av[mi], bv[ni], acc[mi][ni], 0, 0, 0);
    }
    asm volatile("s_waitcnt vmcnt(0)" ::: "memory");
    __syncthreads();
  }

  CS += (size_t)b * 4096 * CCP;
#pragma unroll
  for (int mi = 0; mi < 4; ++mi) {
#pragma unroll
    for (int q = 0; q < 4; ++q) {
      int m = m0 + wm + mi * 16 + lk * 4 + q;
#pragma unroll
      for (int ni = 0; ni < 2; ++ni) {
        int n = n0 + wn + ni * 16 + lr;
        CS[(size_t)m * CCP + n] = (f16)acc[mi][ni][q];
      }
    }
  }
}

// GEMM2: N2[pos][r] = sden[pos] * sum_c CA[pos][c] * P1T[r][c]. NT GEMM,
// 64x128 tile, BK=64, 8 waves, 512 threads. 3-buffer LDS (72 KB -> 2
// blocks/CU), depth-2 counted-vmcnt pipeline (T3/T4 minimum form):
//   top of iter t: s_waitcnt vmcnt(3)  -> STAGE(t) landed (t+1 still flying)
//                  s_barrier           -> all waves past COMPUTE(t-1)
//                  STAGE(t+2)          -> overwrites buf[(t-1)%3], now safe
//                  COMPUTE(t)
// Loads never drain to 0 in the main loop; each stage has ~2 compute phases
// to cover HBM latency. 640 blocks, bijective XCD swizzle (A-panels L2-local).
__global__ __launch_bounds__(512) void k_gemm2(
    const f16* __restrict__ A, const f16* __restrict__ B, f16* __restrict__ C,
    const float* __restrict__ sden) {
  __shared__ f16 tA[3][64 * 64];
  __shared__ f16 tB[3][128 * 64];
  const int tid = threadIdx.x;
  const int l = tid & 63, w = tid >> 6;  // w in [0,8)
  // XCD swizzle: 640 = 8 XCDs x 80. p%8 = XCD; L = xcd*80 + p/8;
  // L = b*320 + mt*5 + nt
  const int p = blockIdx.x;
  const int L = (p & 7) * 80 + (p >> 3);
  const int b = L / 320;
  const int rL = L - b * 320;
  const int mt = rL / 5, nt = rL - mt * 5;
  const int m0 = mt * 64, n0 = nt * 128;
  A += (size_t)b * 4096 * CCP;
  B += (size_t)b * PLP * CCP;
  C += (size_t)b * 4096 * PLP;
  const float* sd = sden + (size_t)b * 4096;

  // staging: A = 8 chunks (64 rows) -> wave w stages chunk w;
  // B = 16 chunks (128 rows) -> wave stages chunks 2w, 2w+1. 3 gld16/thread.
  size_t aOff;
  {
    int li = w * 64 + l;
    int r = li >> 3;
    int j = (li & 7) ^ (r & 7);
    aOff = (size_t)(m0 + r) * CCP + j * 8;
  }
  size_t bOff[2];
  int bCh[2];
#pragma unroll
  for (int i = 0; i < 2; ++i) {
    bCh[i] = w * 2 + i;
    int li = bCh[i] * 64 + l;
    int r = li >> 3;
    int j = (li & 7) ^ (r & 7);
    bOff[i] = (size_t)(n0 + r) * CCP + j * 8;
  }

  const int wm = (w >> 2) * 32, wn = (w & 3) * 32;
  const int lr = l & 15, lk = l >> 4;
  const int xr = (lr & 7) << 4;

  f32x4 acc[2][2];
#pragma unroll
  for (int mi = 0; mi < 2; ++mi)
#pragma unroll
    for (int ni = 0; ni < 2; ++ni) acc[mi][ni] = (f32x4){0.f, 0.f, 0.f, 0.f};

  auto STAGE = [&](int buf, int k0) {
    gld16(A + aOff + k0, (char*)tA[buf] + w * 1024);
#pragma unroll
    for (int i = 0; i < 2; ++i)
      gld16(B + bOff[i] + k0, (char*)tB[buf] + bCh[i] * 1024);
  };
  auto COMPUTE = [&](int buf) {
    __builtin_amdgcn_s_setprio(1);
#pragma unroll
    for (int kk = 0; kk < 2; ++kk) {
      half8 av[2], bv[2];
      const int cb = lk * 16 + kk * 64;
#pragma unroll
      for (int mi = 0; mi < 2; ++mi) {
        int r = wm + mi * 16 + lr;
        av[mi] = *(const half8*)((const char*)tA[buf] + r * 128 + (cb ^ xr));
      }
#pragma unroll
      for (int ni = 0; ni < 2; ++ni) {
        int r = wn + ni * 16 + lr;
        bv[ni] = *(const half8*)((const char*)tB[buf] + r * 128 + (cb ^ xr));
      }
#pragma unroll
      for (int mi = 0; mi < 2; ++mi)
#pragma unroll
        for (int ni = 0; ni < 2; ++ni)
          acc[mi][ni] = __builtin_amdgcn_mfma_f32_16x16x32_f16(
              av[mi], bv[ni], acc[mi][ni], 0, 0, 0);
    }
    __builtin_amdgcn_s_setprio(0);
  };

  const int NT = CCP / 64;  // 62
  STAGE(0, 0);
  STAGE(1, 64);
  int cur = 0, pre = 2, kpre = 128;
#pragma unroll 1
  for (int t = 0; t < NT - 2; ++t) {
    asm volatile("s_waitcnt vmcnt(3)" ::: "memory");
    __builtin_amdgcn_s_barrier();
    STAGE(pre, kpre);
    COMPUTE(cur);
    cur = (cur == 2) ? 0 : cur + 1;
    pre = (pre == 2) ? 0 : pre + 1;
    kpre += 64;
  }
  asm volatile("s_waitcnt vmcnt(3)" ::: "memory");
  __builtin_amdgcn_s_barrier();
  COMPUTE(cur);
  cur = (cur == 2) ? 0 : cur + 1;
  asm volatile("s_waitcnt vmcnt(0)" ::: "memory");
  __builtin_amdgcn_s_barrier();
  COMPUTE(cur);

#pragma unroll
  for (int mi = 0; mi < 2; ++mi) {
#pragma unroll
    for (int q = 0; q < 4; ++q) {
      int m = m0 + wm + mi * 16 + lk * 4 + q;
      float sc = sd[m];
#pragma unroll
      for (int ni = 0; ni < 2; ++ni) {
        int n = n0 + wn + ni * 16 + lr;
        C[(size_t)m * PLP + n] = (f16)(acc[mi][ni][q] * sc);
      }
    }
  }
}

// one-pass stats, fully vectorized: thread t owns 16 contiguous cols.
__global__ __launch_bounds__(256) void k_stats(f16* __restrict__ CS,
                                               const float* __restrict__ k1d,
                                               float* __restrict__ sden) {
  __shared__ float red[8];
  const int tid = threadIdx.x;
  const int row = blockIdx.x, b = blockIdx.y;
  f16* cs = CS + ((size_t)b * 4096 + row) * CCP;
  const float* kd = k1d + (size_t)b * CCP;
  const int base = tid * 16;
  const bool act = base < CCP;  // t < 248

  float tv[16];
  float s1 = 0.f, s2 = 0.f;
  if (act) {
    half8 v0 = ((const half8*)(cs + base))[0];
    half8 v1 = ((const half8*)(cs + base))[1];
    float kv[16];
    *(float4*)(kv + 0) = ((const float4*)(kd + base))[0];
    *(float4*)(kv + 4) = ((const float4*)(kd + base))[1];
    *(float4*)(kv + 8) = ((const float4*)(kd + base))[2];
    *(float4*)(kv + 12) = ((const float4*)(kd + base))[3];
#pragma unroll
    for (int i = 0; i < 16; ++i) {
      float cval = (float)(i < 8 ? v0[i] : v1[i - 8]);
      float t = (base + i < CC) ? (kv[i] - 2.f * cval) : 0.f;
      tv[i] = t;
      s1 += t;
      s2 = fmaf(t, t, s2);
    }
  } else {
#pragma unroll
    for (int i = 0; i < 16; ++i) tv[i] = 0.f;
  }
#pragma unroll
  for (int m = 32; m; m >>= 1) {
    s1 += __shfl_xor(s1, m, 64);
    s2 += __shfl_xor(s2, m, 64);
  }
  if ((tid & 63) == 0) {
    red[tid >> 6] = s1;
    red[4 + (tid >> 6)] = s2;
  }
  __syncthreads();
  float mu = (red[0] + red[1] + red[2] + red[3]) * (1.f / CC);
  float ex2 = (red[4] + red[5] + red[6] + red[7]) * (1.f / CC);
  float var = fmaxf(ex2 - mu * mu, 1e-12f);
  float rsd = rsqrtf(var);
  __syncthreads();

  float den = 0.f;
  if (act) {
    half8 w0, w1;
#pragma unroll
    for (int i = 0; i < 16; ++i) {
      float wv = 0.f;
      if (base + i < CC) {
        float z = (tv[i] - mu) * rsd;
        float e2z = __expf(2.f * z);
        float th = 1.f - 2.f / (e2z + 1.f);  // tanh(z)
        wv = __expf(-LAM * th);
        den += wv;
      }
      if (i < 8) w0[i] = (f16)wv; else w1[i - 8] = (f16)wv;
    }
    ((half8*)(cs + base))[0] = w0;
    ((half8*)(cs + base))[1] = w1;
  }
#pragma unroll
  for (int m = 32; m; m >>= 1) den += __shfl_xor(den, m, 64);
  if ((tid & 63) == 0) red[tid >> 6] = den;
  __syncthreads();
  if (tid == 0)
    sden[(size_t)b * 4096 + row] = 1.f / (9.f * (red[0] + red[1] + red[2] + red[3]));
}

// gather 9-neighbor numerators (already normalized), mask-gate, 1x1 conv, ELU
__global__ __launch_bounds__(256) void k_final2(
    const float* __restrict__ bg_in, const float* __restrict__ mask,
    const f16* __restrict__ N2, const float* __restrict__ Wml,
    const float* __restrict__ bml, float* __restrict__ out) {
  __shared__ float s_con[4 * 128];
  const int tid = threadIdx.x;
  const int posg = blockIdx.x * 4;
  for (int i = tid; i < 4 * 128; i += 256) {
    int p = i >> 7, c = i & 127;
    int pos = posg + p;
    float v;
    if (c < 64) {
      v = bg_in[(size_t)pos * DD + c];
    } else {
      int cc = c - 64;
      int bwx = pos & 4095, bb = pos >> 12;
      int y = bwx >> 6, x = bwx & 63;
      float a = 0.f;
#pragma unroll
      for (int s = 0; s < 3; ++s) {
        int yy = y + 1 - s;
        if (yy < 0 || yy >= HH) continue;
#pragma unroll
        for (int t = 0; t < 3; ++t) {
          int xx = x + 1 - t;
          if (xx < 0 || xx >= WW) continue;
          a += (float)N2[((size_t)bb * 4096 + yy * 64 + xx) * PLP + (s * 3 + t) * 64 + cc];
        }
      }
      float m0 = mask[(size_t)pos * DD];
      v = bg_in[(size_t)pos * DD + cc] * m0 + a * (1.f - m0);
    }
    s_con[i] = v;
  }
  __syncthreads();
  const int o = tid & 63, p = tid >> 6;
  float sum = bml[o];
  const float* cp = s_con + (p << 7);
#pragma unroll 8
  for (int c = 0; c < 128; ++c) sum = fmaf(cp[c], Wml[c * 64 + o], sum);
  out[(size_t)(posg + p) * 64 + o] = (sum > 0.f) ? sum : expm1f(sum);
}

// ======================= FALLBACK PATH (round-1, known-good) ==================
#define WS_BG    0
#define WS_BGT   524288
#define WS_K1D   1048576
#define WS_ACLN  1056264

__global__ __launch_bounds__(256) void k_prep(
    const float* __restrict__ bg_in, const float* __restrict__ mask,
    float* __restrict__ bg, float* __restrict__ bgT) {
  int idx = blockIdx.x * 256 + threadIdx.x;
  if (idx >= BB * HH * WW * DD) return;
  int ch = idx & 63, pos = idx >> 6;
  float m = mask[(size_t)pos * DD];
  float v = bg_in[idx] * m;
  bg[idx] = v;
  int x = pos & 63, rest = pos >> 6;
  int y = rest & 63, b = rest >> 6;
  bgT[(((size_t)b * DD + ch) * HH + y) * WW + x] = v;
}

__global__ __launch_bounds__(256) void k_k1d(const float* __restrict__ bg,
                                             float* __restrict__ k1d) {
  int idx = blockIdx.x * 256 + threadIdx.x;
  if (idx >= BB * CC) return;
  int b = idx / CC, c = idx - b * CC;
  int ci = c / PH, cj = c - ci * PH;
  float s = 0.f;
  for (int ki = 0; ki < 3; ++ki)
    for (int kj = 0; kj < 3; ++kj) {
      const float4* p =
          (const float4*)(bg + (((size_t)(b * HH + ci + ki) * WW) + cj + kj) * DD);
#pragma unroll
      for (int q = 0; q < 16; ++q) {
        float4 v = p[q];
        s += v.x * v.x + v.y * v.y + v.z * v.z + v.w * v.w;
      }
    }
  k1d[idx] = s;
}

__global__ __launch_bounds__(256, 2) void k_heavy(
    const float* __restrict__ fg, const float* __restrict__ bg,
    const float* __restrict__ bgT, const float* __restrict__ k1d,
    float* __restrict__ acln) {
  __shared__ _Float16 s_cs[TP * CC];
  __shared__ float s_fg[TP * PL];
  __shared__ float s_red[8];
  __shared__ float s_wwd[TP];
  __shared__ float s_den[TP];

  const int tid = threadIdx.x;
  const int X0 = blockIdx.x * TP;
  const int Y = blockIdx.y;
  const int b = blockIdx.z;

  for (int i = tid; i < TP * PL; i += 256) {
    int p = i / PL, r = i - p * PL;
    int kk = r >> 6, ch = r & 63;
    int ki = kk / 3, kj = kk - 3 * ki;
    int hy = Y + ki - 1, wx = X0 + p + kj - 1;
    float v = 0.f;
    if (hy >= 0 && hy < HH && wx >= 0 && wx < WW)
      v = fg[(((size_t)b * HH + hy) * WW + wx) * DD + ch];
    s_fg[i] = v;
  }
  __syncthreads();
  {
    int p = tid >> 5, lane = tid & 31;
    float a = 0.f;
    for (int r = lane; r < PL; r += 32) {
      float v = s_fg[p * PL + r];
      a = fmaf(v, v, a);
    }
#pragma unroll
    for (int m = 16; m; m >>= 1) a += __shfl_xor(a, m, 64);
    if (lane == 0) s_wwd[p] = a;
  }
  __syncthreads();

  const float* bgTb = bgT + (size_t)b * DD * HH * WW;
  for (int sw = 0; sw < 4; ++sw) {
    const int cb = sw * 256 + tid;
    float acc[TP][4];
#pragma unroll
    for (int p = 0; p < TP; ++p)
#pragma unroll
      for (int q = 0; q < 4; ++q) acc[p][q] = 0.f;
    int off4[4];
#pragma unroll
    for (int q = 0; q < 4; ++q) {
      int c = cb + q * 1024;
      if (c >= CC) c = CC - 1;
      int ci = c / PH;
      off4[q] = ci * WW + (c - ci * PH);
    }
    for (int ch = 0; ch < DD; ++ch) {
      const float* bgTc = bgTb + (size_t)ch * (HH * WW);
#pragma unroll
      for (int kk = 0; kk < 9; ++kk) {
        const int ki = kk / 3, kj = kk - 3 * (kk / 3);
        float fv[TP];
#pragma unroll
        for (int p = 0; p < TP; ++p) fv[p] = s_fg[p * PL + (kk << 6) + ch];
        float bv[4];
#pragma unroll
        for (int q = 0; q < 4; ++q) bv[q] = bgTc[off4[q] + ki * WW + kj];
#pragma unroll
        for (int p = 0; p < TP; ++p)
#pragma unroll
          for (int q = 0; q < 4; ++q) acc[p][q] = fmaf(fv[p], bv[q], acc[p][q]);
      }
    }
#pragma unroll
    for (int q = 0; q < 4; ++q) {
      int c = cb + q * 1024;
      if (c < CC) {
#pragma unroll
        for (int p = 0; p < TP; ++p) s_cs[p * CC + c] = (_Float16)acc[p][q];
      }
    }
  }
  __syncthreads();

  const float* k1db = k1d + b * CC;
  for (int pos = 0; pos < TP; ++pos) {
    __syncthreads();
    const float wwdp = s_wwd[pos];
    float s1 = 0.f, s2 = 0.f;
    for (int c = tid; c < CC; c += 256) {
      float ds1 = k1db[c] + wwdp - 2.f * (float)s_cs[pos * CC + c];
      s1 += ds1;
      s2 = fmaf(ds1, ds1, s2);
    }
#pragma unroll
    for (int m = 32; m; m >>= 1) {
      s1 += __shfl_xor(s1, m, 64);
      s2 += __shfl_xor(s2, m, 64);
    }
    if ((tid & 63) == 0) {
      int w = tid >> 6;
      s_red[w] = s1;
      s_red[4 + w] = s2;
    }
    __syncthreads();
    float mu = (s_red[0] + s_red[1] + s_red[2] + s_red[3]) * (1.f / CC);
    float ex2 = (s_red[4] + s_red[5] + s_red[6] + s_red[7]) * (1.f / CC);
    float var = fmaxf(ex2 - mu * mu, 1e-12f);
    float rsd = rsqrtf(var);
    float dp = 0.f;
    for (int c = tid; c < CC; c += 256) {
      float ds1 = k1db[c] + wwdp - 2.f * (float)s_cs[pos * CC + c];
      float z = (ds1 - mu) * rsd;
      float wv = expf(-LAM * tanhf(z));
      s_cs[pos * CC + c] = (_Float16)wv;
      dp += wv;
    }
#pragma unroll
    for (int m = 32; m; m >>= 1) dp += __shfl_xor(dp, m, 64);
    __syncthreads();
    if ((tid & 63) == 0) s_red[tid >> 6] = dp;
    __syncthreads();
    if (tid == 0) s_den[pos] = s_red[0] + s_red[1] + s_red[2] + s_red[3];
  }

  const int d = tid & 63;
  const int grp = tid >> 6;
  const int oA = grp, oB = grp + 4;
  const int sA = oA / 3, tA = oA - 3 * sA;
  const int sB = oB / 3, tB = oB - 3 * sB;
  const bool hasC = (grp == 0);
  const int offA = (sA * WW + tA) * DD + d;
  const int offB = (sB * WW + tB) * DD + d;
  const int offC = (2 * WW + 2) * DD + d;
  float aA[TP], aB[TP], aC[TP];
#pragma unroll
  for (int p = 0; p < TP; ++p) { aA[p] = 0.f; aB[p] = 0.f; aC[p] = 0.f; }
  const float* bgb = bg + (size_t)b * HH * WW * DD;
  float* s_wf = s_fg;
  int cj = 0, rowoff = 0;
  for (int c0 = 0; c0 < CC; c0 += 128) {
    const int n = (CC - c0 < 128) ? (CC - c0) : 128;
    __syncthreads();
    for (int i = tid; i < TP * 128; i += 256) {
      int p = i >> 7, cc = i & 127;
      s_wf[i] = (cc < n) ? (float)s_cs[p * CC + c0 + cc] : 0.f;
    }
    __syncthreads();
    for (int cc = 0; cc < n; cc += 2) {
      float2 wv[TP];
#pragma unroll
      for (int p = 0; p < TP; ++p)
        wv[p] = *(const float2*)(s_wf + (p << 7) + cc);
      {
        const float* rp = bgb + (size_t)rowoff * DD;
        float bA = rp[offA], bB = rp[offB], bCv = rp[offC];
#pragma unroll
        for (int p = 0; p < TP; ++p) {
          aA[p] = fmaf(wv[p].x, bA, aA[p]);
          aB[p] = fmaf(wv[p].x, bB, aB[p]);
          if (hasC) aC[p] = fmaf(wv[p].x, bCv, aC[p]);
        }
        ++rowoff;
        if (++cj == PH) { cj = 0; rowoff += 2; }
      }
      {
        const float* rp = bgb + (size_t)rowoff * DD;
        float bA = rp[offA], bB = rp[offB], bCv = rp[offC];
#pragma unroll
        for (int p = 0; p < TP; ++p) {
          aA[p] = fmaf(wv[p].y, bA, aA[p]);
          aB[p] = fmaf(wv[p].y, bB, aB[p]);
          if (hasC) aC[p] = fmaf(wv[p].y, bCv, aC[p]);
        }
        ++rowoff;
        if (++cj == PH) { cj = 0; rowoff += 2; }
      }
    }
  }
  __syncthreads();
#pragma unroll
  for (int p = 0; p < TP; ++p) {
    const float inv = 1.f / (9.f * s_den[p]);
    float* dst = acln + ((((size_t)b * HH + Y) * WW + (X0 + p)) * 9) * 64;
    dst[oA * 64 + d] = aA[p] * inv;
    dst[oB * 64 + d] = aB[p] * inv;
    if (hasC) dst[512 + d] = aC[p] * inv;
  }
}

__global__ __launch_bounds__(256) void k_final(
    const float* __restrict__ bg_in, const float* __restrict__ mask,
    const float* __restrict__ bg, const float* __restrict__ acln,
    const float* __restrict__ Wml, const float* __restrict__ bml,
    float* __restrict__ out) {
  __shared__ float s_con[4 * 128];
  const int tid = threadIdx.x;
  const int posg = blockIdx.x * 4;
  for (int i = tid; i < 4 * 128; i += 256) {
    int p = i >> 7, c = i & 127;
    int pos = posg + p;
    float v;
    if (c < 64) {
      v = bg_in[(size_t)pos * DD + c];
    } else {
      int cc = c - 64;
      int bwx = pos & 4095, bb = pos >> 12;
      int y = bwx >> 6, x = bwx & 63;
      float a = 0.f;
#pragma unroll
      for (int s = 0; s < 3; ++s) {
        int yy = y + 1 - s;
        if (yy < 0 || yy >= HH) continue;
#pragma unroll
        for (int t = 0; t < 3; ++t) {
          int xx = x + 1 - t;
          if (xx < 0 || xx >= WW) continue;
          a += acln[((((size_t)bb * HH + yy) * WW + xx) * 9 + (s * 3 + t)) * 64 + cc];
        }
      }
      float m0 = mask[(size_t)pos * DD];
      v = bg[(size_t)pos * DD + cc] + a * (1.f - m0);
    }
    s_con[i] = v;
  }
  __syncthreads();
  const int o = tid & 63, p = tid >> 6;
  float sum = bml[o];
  const float* cp = s_con + (p << 7);
#pragma unroll 8
  for (int c = 0; c < 128; ++c) sum = fmaf(cp[c], Wml[c * 64 + o], sum);
  out[(size_t)(posg + p) * 64 + o] = (sum > 0.f) ? sum : expm1f(sum);
}

// =============================== launch ===============================
extern "C" void kernel_launch(void* const* d_in, const int* in_sizes, int n_in,
                              void* d_out, int out_size, void* d_ws, size_t ws_size,
                              hipStream_t stream) {
  const float* bg_in = (const float*)d_in[0];
  const float* fg_in = (const float*)d_in[1];
  const float* mask = (const float*)d_in[2];
  const float* Wml = (const float*)d_in[3];
  const float* bml = (const float*)d_in[4];
  float* out = (float*)d_out;

  if (ws_size >= REQ_FAST) {
    char* w8 = (char*)d_ws;
    f16* fgp = (f16*)(w8 + 2097152);
    f16* bgf = (f16*)(w8 + 3212288);
    f16* P1T = (f16*)(w8 + 4310016);
    f16* CS = (f16*)(w8 + 14468096);
    f16* N2 = (f16*)(w8 + 79479808);
    float* k1d = (float*)(w8 + 89965568);
    float* sden = (float*)(w8 + 89997312);

    const int NPREP =
        BB * 4288 * 64 + BB * 4356 * 64 + BB * PLP * CCP + BB * CC;
    k_preall<<<dim3((NPREP + 255) / 256), dim3(256), 0, stream>>>(
        bg_in, fg_in, mask, bgf, fgp, P1T, k1d);
    k_gemm1<<<dim3(CCP / 128, 32, 2), dim3(512), 0, stream>>>(fgp, bgf, CS);
    k_stats<<<dim3(4096, 2), dim3(256), 0, stream>>>(CS, k1d, sden);
    k_gemm2<<<dim3(640), dim3(512), 0, stream>>>(CS, P1T, N2, sden);
    k_final2<<<dim3(2048), dim3(256), 0, stream>>>(bg_in, mask, N2, Wml, bml, out);
  } else {
    float* ws = (float*)d_ws;
    float* bg = ws + WS_BG;
    float* bgT = ws + WS_BGT;
    float* k1d = ws + WS_K1D;
    float* acln = ws + WS_ACLN;
    k_prep<<<dim3(2048), dim3(256), 0, stream>>>(bg_in, mask, bg, bgT);
    k_k1d<<<dim3((BB * CC + 255) / 256), dim3(256), 0, stream>>>(bg, k1d);
    k_heavy<<<dim3(8, 64, 2), dim3(256), 0, stream>>>(fg_in, bg, bgT, k1d, acln);
    k_final<<<dim3(2048), dim3(256), 0, stream>>>(bg_in, mask, bg, acln, Wml, bml, out);
  }
}

// Round 10
// 205.822 us; speedup vs baseline: 1.1496x; 1.1496x over previous
//
#include <hip/hip_runtime.h>
#include <hip/hip_fp16.h>
#include <math.h>

// Problem constants
#define BB 2
#define HH 64
#define WW 64
#define DD 64
#define PH 62          // (H-K)/stride+1
#define CC 3844        // PH*PH
#define CCP 3968       // CC padded to mult of 128
#define PL 576         // K*K*D
#define PLP 640        // PL padded to mult of 128
#define TP 8
#define LAM 10.0f

typedef _Float16 f16;
typedef __attribute__((ext_vector_type(8))) _Float16 half8;
typedef __attribute__((ext_vector_type(4))) float f32x4;

// ======================= FAST PATH (MFMA) =======================
// ws layout (bytes) — bg f32 region retained for fallback-compat but unused:
//  bg   f32 [2][4096][64]       @ 0           2,097,152   (UNUSED in fast path)
//  fgp  f16 [2][4356][64]       @ 2,097,152   1,115,136   (66x66 padded fg image)
//  bgf  f16 [2][4288][64]       @ 3,212,288   1,097,728   (bg pixels + zero page)
//  P1T  f16 [2][640][3968]      @ 4,310,016   10,158,080
//  CS   f16 [2][4096][3968]     @ 14,468,096  65,011,712
//  N2   f16 [2][4096][640]      @ 79,479,808  10,485,760
//  k1d  f32 [2][3968]           @ 89,965,568  31,744
//  sden f32 [2][4096]           @ 89,997,312  32,768
#define REQ_FAST 90030080ULL

__device__ __forceinline__ void gld16(const void* g, void* l) {
  __builtin_amdgcn_global_load_lds((const __attribute__((address_space(1))) void*)g,
                                   (__attribute__((address_space(3))) void*)l, 16, 0, 0);
}

// merged prep: bgf (masked f16 + zero page), fgp (padded fg f16),
// P1T (im2col^T from bg_in*mask), k1d (patch norms) — all independent ranges.
__global__ __launch_bounds__(256) void k_preall(
    const float* __restrict__ bg_in, const float* __restrict__ fg,
    const float* __restrict__ mask, f16* __restrict__ bgf,
    f16* __restrict__ fgp, f16* __restrict__ P1T, float* __restrict__ k1d) {
  const int NBG = BB * 4288 * 64;
  const int NFG = BB * 4356 * 64;
  const int NP1T = BB * PLP * CCP;
  int idx = blockIdx.x * 256 + threadIdx.x;
  if (idx < NBG) {
    int ch = idx & 63;
    int pix = (idx >> 6) % 4288;
    int b = idx / (4288 * 64);
    f16 v = (f16)0.f;
    if (pix < 4096) {
      size_t src = ((size_t)b * 4096 + pix) * 64 + ch;
      v = (f16)(bg_in[src] * mask[((size_t)b * 4096 + pix) * 64]);
    }
    bgf[idx] = v;
  } else if (idx < NBG + NFG) {
    int i2 = idx - NBG;
    int ch = i2 & 63;
    int pix = (i2 >> 6) % 4356;
    int b = i2 / (4356 * 64);
    int yy = pix / 66, xx = pix - 66 * yy;
    float v = 0.f;
    if (yy >= 1 && yy <= 64 && xx >= 1 && xx <= 64)
      v = fg[(((size_t)b * 64 + (yy - 1)) * 64 + (xx - 1)) * 64 + ch];
    fgp[i2] = (f16)v;
  } else if (idx < NBG + NFG + NP1T) {
    int i3 = idx - (NBG + NFG);
    int c = i3 % CCP;
    int rest = i3 / CCP;
    int r = rest % PLP, b = rest / PLP;
    float v = 0.f;
    if (r < PL && c < CC) {
      int ci = c / PH, cj = c - ci * PH;
      int kk = r >> 6, ch = r & 63;
      int ki = kk / 3, kj = kk - 3 * ki;
      int pix = (ci + ki) * WW + cj + kj;
      v = bg_in[((size_t)b * 4096 + pix) * 64 + ch] *
          mask[((size_t)b * 4096 + pix) * 64];
    }
    P1T[i3] = (f16)v;
  } else if (idx < NBG + NFG + NP1T + BB * CC) {
    int i4 = idx - (NBG + NFG + NP1T);
    int b = i4 / CC, c = i4 - b * CC;
    int ci = c / PH, cj = c - ci * PH;
    float s = 0.f;
    for (int ki = 0; ki < 3; ++ki)
      for (int kj = 0; kj < 3; ++kj) {
        int pix = (ci + ki) * WW + cj + kj;
        float m = mask[((size_t)b * 4096 + pix) * 64];
        float m2 = m * m;
        const float4* p = (const float4*)(bg_in + ((size_t)b * 4096 + pix) * 64);
#pragma unroll
        for (int q = 0; q < 16; ++q) {
          float4 v = p[q];
          s += m2 * (v.x * v.x + v.y * v.y + v.z * v.z + v.w * v.w);
        }
      }
    k1d[(size_t)b * CCP + c] = s;
  }
}

// GEMM1: CS[pos][c] = dot(fg patch pos, bg patch c). A,B staged directly from
// padded f16 images (BK=64 == one (ki,kj) tap). 128x128 tile, 8 waves (2x4,
// wave tile 64x32), 512 threads, dbuf LDS 64 KB -> 2 blocks/CU = 16 waves/CU.
__global__ __launch_bounds__(512) void k_gemm1(
    const f16* __restrict__ fgp, const f16* __restrict__ bgf,
    f16* __restrict__ CS) {
  __shared__ f16 tA[2][128 * 64];
  __shared__ f16 tB[2][128 * 64];
  const int tid = threadIdx.x;
  const int l = tid & 63, w = tid >> 6;  // w in [0,8)
  const int b = blockIdx.z;
  const int m0 = blockIdx.y * 128, n0 = blockIdx.x * 128;
  const f16* fgB = fgp + (size_t)b * (4356 * 64);
  const f16* bgB = bgf + (size_t)b * (4288 * 64);

  int pixA[2], chSA[2], aCh[2];
#pragma unroll
  for (int i = 0; i < 2; ++i) {
    aCh[i] = w * 2 + i;
    int li = aCh[i] * 64 + l;
    int r = li >> 3;
    int j = (li & 7) ^ (r & 7);
    chSA[i] = j * 8;
    int pos = m0 + r;
    pixA[i] = (pos >> 6) * 66 + (pos & 63);
  }
  int pixB[2], chSB[2], bCh[2];
#pragma unroll
  for (int i = 0; i < 2; ++i) {
    bCh[i] = w * 2 + i;
    int li = bCh[i] * 64 + l;
    int r = li >> 3;
    int j = (li & 7) ^ (r & 7);
    chSB[i] = j * 8;
    int c = n0 + r;
    if (c < CC) {
      int ci = c / 62;
      pixB[i] = ci * 64 + (c - 62 * ci);
    } else {
      pixB[i] = 4096;  // zero page
    }
  }

  const int wm = (w >> 2) * 64, wn = (w & 3) * 32;
  const int lr = l & 15, lk = l >> 4;
  const int xr = (lr & 7) << 4;

  f32x4 acc[4][2];
#pragma unroll
  for (int mi = 0; mi < 4; ++mi)
#pragma unroll
    for (int ni = 0; ni < 2; ++ni) acc[mi][ni] = (f32x4){0.f, 0.f, 0.f, 0.f};

#pragma unroll
  for (int i = 0; i < 2; ++i) {
    gld16(fgB + (size_t)pixA[i] * 64 + chSA[i], (char*)tA[0] + aCh[i] * 1024);
    gld16(bgB + (size_t)pixB[i] * 64 + chSB[i], (char*)tB[0] + bCh[i] * 1024);
  }
  asm volatile("s_waitcnt vmcnt(0)" ::: "memory");
  __syncthreads();

#pragma unroll 1
  for (int t = 0; t < 9; ++t) {
    const int cur = t & 1;
    if (t + 1 < 9) {
      const int tn = t + 1;
      const int ki = tn / 3, kj = tn - 3 * ki;
      const int offA = ki * 66 + kj, offB = ki * 64 + kj;
#pragma unroll
      for (int i = 0; i < 2; ++i) {
        gld16(fgB + (size_t)(pixA[i] + offA) * 64 + chSA[i],
              (char*)tA[cur ^ 1] + aCh[i] * 1024);
        gld16(bgB + (size_t)(pixB[i] + offB) * 64 + chSB[i],
              (char*)tB[cur ^ 1] + bCh[i] * 1024);
      }
    }
#pragma unroll
    for (int kk = 0; kk < 2; ++kk) {
      half8 av[4], bv[2];
      const int cb = lk * 16 + kk * 64;
#pragma unroll
      for (int mi = 0; mi < 4; ++mi) {
        int r = wm + mi * 16 + lr;
        av[mi] = *(const half8*)((const char*)tA[cur] + r * 128 + (cb ^ xr));
      }
#pragma unroll
      for (int ni = 0; ni < 2; ++ni) {
        int r = wn + ni * 16 + lr;
        bv[ni] = *(const half8*)((const char*)tB[cur] + r * 128 + (cb ^ xr));
      }
#pragma unroll
      for (int mi = 0; mi < 4; ++mi)
#pragma unroll
        for (int ni = 0; ni < 2; ++ni)
          acc[mi][ni] = __builtin_amdgcn_mfma_f32_16x16x32_f16(
              av[mi], bv[ni], acc[mi][ni], 0, 0, 0);
    }
    asm volatile("s_waitcnt vmcnt(0)" ::: "memory");
    __syncthreads();
  }

  CS += (size_t)b * 4096 * CCP;
#pragma unroll
  for (int mi = 0; mi < 4; ++mi) {
#pragma unroll
    for (int q = 0; q < 4; ++q) {
      int m = m0 + wm + mi * 16 + lk * 4 + q;
#pragma unroll
      for (int ni = 0; ni < 2; ++ni) {
        int n = n0 + wn + ni * 16 + lr;
        CS[(size_t)m * CCP + n] = (f16)acc[mi][ni][q];
      }
    }
  }
}

// GEMM2 (R8 known-good form): N2[pos][r] = sden[pos]*sum_c CA[pos][c]*P1T[r][c].
// NT GEMM, 64x128 tile, BK=64, 8 waves (2x4, wave tile 32x32), 512 threads,
// dbuf LDS 48 KB -> 3 blocks/CU = 24 waves/CU. 640 blocks, bijective XCD
// swizzle: each XCD gets 16 consecutive m-tiles x 5 n-tiles (A L2-local).
// NOTE: counted-vmcnt pipelines tried twice (R5: 4-buf 128KB, R9: 3-buf 72KB)
// — both regressed by trading occupancy for depth. 2-phase + max TLP wins.
__global__ __launch_bounds__(512) void k_gemm2(
    const f16* __restrict__ A, const f16* __restrict__ B, f16* __restrict__ C,
    const float* __restrict__ sden) {
  __shared__ f16 tA[2][64 * 64];
  __shared__ f16 tB[2][128 * 64];
  const int tid = threadIdx.x;
  const int l = tid & 63, w = tid >> 6;  // w in [0,8)
  const int p = blockIdx.x;
  const int L = (p & 7) * 80 + (p >> 3);
  const int b = L / 320;
  const int rL = L - b * 320;
  const int mt = rL / 5, nt = rL - mt * 5;
  const int m0 = mt * 64, n0 = nt * 128;
  A += (size_t)b * 4096 * CCP;
  B += (size_t)b * PLP * CCP;
  C += (size_t)b * 4096 * PLP;
  const float* sd = sden + (size_t)b * 4096;

  size_t aOff;
  {
    int li = w * 64 + l;
    int r = li >> 3;
    int j = (li & 7) ^ (r & 7);
    aOff = (size_t)(m0 + r) * CCP + j * 8;
  }
  size_t bOff[2];
  int bCh[2];
#pragma unroll
  for (int i = 0; i < 2; ++i) {
    bCh[i] = w * 2 + i;
    int li = bCh[i] * 64 + l;
    int r = li >> 3;
    int j = (li & 7) ^ (r & 7);
    bOff[i] = (size_t)(n0 + r) * CCP + j * 8;
  }

  const int wm = (w >> 2) * 32, wn = (w & 3) * 32;
  const int lr = l & 15, lk = l >> 4;
  const int xr = (lr & 7) << 4;

  f32x4 acc[2][2];
#pragma unroll
  for (int mi = 0; mi < 2; ++mi)
#pragma unroll
    for (int ni = 0; ni < 2; ++ni) acc[mi][ni] = (f32x4){0.f, 0.f, 0.f, 0.f};

  auto STAGE = [&](int buf, int k0) {
    gld16(A + aOff + k0, (char*)tA[buf] + w * 1024);
#pragma unroll
    for (int i = 0; i < 2; ++i)
      gld16(B + bOff[i] + k0, (char*)tB[buf] + bCh[i] * 1024);
  };

  const int NT = CCP / 64;  // 62
  STAGE(0, 0);
  asm volatile("s_waitcnt vmcnt(0)" ::: "memory");
  __syncthreads();

#pragma unroll 1
  for (int t = 0; t < NT; ++t) {
    const int cur = t & 1;
    if (t + 1 < NT) STAGE(cur ^ 1, (t + 1) * 64);
#pragma unroll
    for (int kk = 0; kk < 2; ++kk) {
      half8 av[2], bv[2];
      const int cb = lk * 16 + kk * 64;
#pragma unroll
      for (int mi = 0; mi < 2; ++mi) {
        int r = wm + mi * 16 + lr;
        av[mi] = *(const half8*)((const char*)tA[cur] + r * 128 + (cb ^ xr));
      }
#pragma unroll
      for (int ni = 0; ni < 2; ++ni) {
        int r = wn + ni * 16 + lr;
        bv[ni] = *(const half8*)((const char*)tB[cur] + r * 128 + (cb ^ xr));
      }
#pragma unroll
      for (int mi = 0; mi < 2; ++mi)
#pragma unroll
        for (int ni = 0; ni < 2; ++ni)
          acc[mi][ni] = __builtin_amdgcn_mfma_f32_16x16x32_f16(
              av[mi], bv[ni], acc[mi][ni], 0, 0, 0);
    }
    asm volatile("s_waitcnt vmcnt(0)" ::: "memory");
    __syncthreads();
  }

#pragma unroll
  for (int mi = 0; mi < 2; ++mi) {
#pragma unroll
    for (int q = 0; q < 4; ++q) {
      int m = m0 + wm + mi * 16 + lk * 4 + q;
      float sc = sd[m];
#pragma unroll
      for (int ni = 0; ni < 2; ++ni) {
        int n = n0 + wn + ni * 16 + lr;
        C[(size_t)m * PLP + n] = (f16)(acc[mi][ni][q] * sc);
      }
    }
  }
}

// one-pass stats, fully vectorized: thread t owns 16 contiguous cols.
__global__ __launch_bounds__(256) void k_stats(f16* __restrict__ CS,
                                               const float* __restrict__ k1d,
                                               float* __restrict__ sden) {
  __shared__ float red[8];
  const int tid = threadIdx.x;
  const int row = blockIdx.x, b = blockIdx.y;
  f16* cs = CS + ((size_t)b * 4096 + row) * CCP;
  const float* kd = k1d + (size_t)b * CCP;
  const int base = tid * 16;
  const bool act = base < CCP;  // t < 248

  float tv[16];
  float s1 = 0.f, s2 = 0.f;
  if (act) {
    half8 v0 = ((const half8*)(cs + base))[0];
    half8 v1 = ((const half8*)(cs + base))[1];
    float kv[16];
    *(float4*)(kv + 0) = ((const float4*)(kd + base))[0];
    *(float4*)(kv + 4) = ((const float4*)(kd + base))[1];
    *(float4*)(kv + 8) = ((const float4*)(kd + base))[2];
    *(float4*)(kv + 12) = ((const float4*)(kd + base))[3];
#pragma unroll
    for (int i = 0; i < 16; ++i) {
      float cval = (float)(i < 8 ? v0[i] : v1[i - 8]);
      float t = (base + i < CC) ? (kv[i] - 2.f * cval) : 0.f;
      tv[i] = t;
      s1 += t;
      s2 = fmaf(t, t, s2);
    }
  } else {
#pragma unroll
    for (int i = 0; i < 16; ++i) tv[i] = 0.f;
  }
#pragma unroll
  for (int m = 32; m; m >>= 1) {
    s1 += __shfl_xor(s1, m, 64);
    s2 += __shfl_xor(s2, m, 64);
  }
  if ((tid & 63) == 0) {
    red[tid >> 6] = s1;
    red[4 + (tid >> 6)] = s2;
  }
  __syncthreads();
  float mu = (red[0] + red[1] + red[2] + red[3]) * (1.f / CC);
  float ex2 = (red[4] + red[5] + red[6] + red[7]) * (1.f / CC);
  float var = fmaxf(ex2 - mu * mu, 1e-12f);
  float rsd = rsqrtf(var);
  __syncthreads();

  float den = 0.f;
  if (act) {
    half8 w0, w1;
#pragma unroll
    for (int i = 0; i < 16; ++i) {
      float wv = 0.f;
      if (base + i < CC) {
        float z = (tv[i] - mu) * rsd;
        float e2z = __expf(2.f * z);
        float th = 1.f - 2.f / (e2z + 1.f);  // tanh(z)
        wv = __expf(-LAM * th);
        den += wv;
      }
      if (i < 8) w0[i] = (f16)wv; else w1[i - 8] = (f16)wv;
    }
    ((half8*)(cs + base))[0] = w0;
    ((half8*)(cs + base))[1] = w1;
  }
#pragma unroll
  for (int m = 32; m; m >>= 1) den += __shfl_xor(den, m, 64);
  if ((tid & 63) == 0) red[tid >> 6] = den;
  __syncthreads();
  if (tid == 0)
    sden[(size_t)b * 4096 + row] = 1.f / (9.f * (red[0] + red[1] + red[2] + red[3]));
}

// gather 9-neighbor numerators (already normalized), mask-gate, 1x1 conv, ELU
__global__ __launch_bounds__(256) void k_final2(
    const float* __restrict__ bg_in, const float* __restrict__ mask,
    const f16* __restrict__ N2, const float* __restrict__ Wml,
    const float* __restrict__ bml, float* __restrict__ out) {
  __shared__ float s_con[4 * 128];
  const int tid = threadIdx.x;
  const int posg = blockIdx.x * 4;
  for (int i = tid; i < 4 * 128; i += 256) {
    int p = i >> 7, c = i & 127;
    int pos = posg + p;
    float v;
    if (c < 64) {
      v = bg_in[(size_t)pos * DD + c];
    } else {
      int cc = c - 64;
      int bwx = pos & 4095, bb = pos >> 12;
      int y = bwx >> 6, x = bwx & 63;
      float a = 0.f;
#pragma unroll
      for (int s = 0; s < 3; ++s) {
        int yy = y + 1 - s;
        if (yy < 0 || yy >= HH) continue;
#pragma unroll
        for (int t = 0; t < 3; ++t) {
          int xx = x + 1 - t;
          if (xx < 0 || xx >= WW) continue;
          a += (float)N2[((size_t)bb * 4096 + yy * 64 + xx) * PLP + (s * 3 + t) * 64 + cc];
        }
      }
      float m0 = mask[(size_t)pos * DD];
      v = bg_in[(size_t)pos * DD + cc] * m0 + a * (1.f - m0);
    }
    s_con[i] = v;
  }
  __syncthreads();
  const int o = tid & 63, p = tid >> 6;
  float sum = bml[o];
  const float* cp = s_con + (p << 7);
#pragma unroll 8
  for (int c = 0; c < 128; ++c) sum = fmaf(cp[c], Wml[c * 64 + o], sum);
  out[(size_t)(posg + p) * 64 + o] = (sum > 0.f) ? sum : expm1f(sum);
}

// ======================= FALLBACK PATH (round-1, known-good) ==================
#define WS_BG    0
#define WS_BGT   524288
#define WS_K1D   1048576
#define WS_ACLN  1056264

__global__ __launch_bounds__(256) void k_prep(
    const float* __restrict__ bg_in, const float* __restrict__ mask,
    float* __restrict__ bg, float* __restrict__ bgT) {
  int idx = blockIdx.x * 256 + threadIdx.x;
  if (idx >= BB * HH * WW * DD) return;
  int ch = idx & 63, pos = idx >> 6;
  float m = mask[(size_t)pos * DD];
  float v = bg_in[idx] * m;
  bg[idx] = v;
  int x = pos & 63, rest = pos >> 6;
  int y = rest & 63, b = rest >> 6;
  bgT[(((size_t)b * DD + ch) * HH + y) * WW + x] = v;
}

__global__ __launch_bounds__(256) void k_k1d(const float* __restrict__ bg,
                                             float* __restrict__ k1d) {
  int idx = blockIdx.x * 256 + threadIdx.x;
  if (idx >= BB * CC) return;
  int b = idx / CC, c = idx - b * CC;
  int ci = c / PH, cj = c - ci * PH;
  float s = 0.f;
  for (int ki = 0; ki < 3; ++ki)
    for (int kj = 0; kj < 3; ++kj) {
      const float4* p =
          (const float4*)(bg + (((size_t)(b * HH + ci + ki) * WW) + cj + kj) * DD);
#pragma unroll
      for (int q = 0; q < 16; ++q) {
        float4 v = p[q];
        s += v.x * v.x + v.y * v.y + v.z * v.z + v.w * v.w;
      }
    }
  k1d[idx] = s;
}

__global__ __launch_bounds__(256, 2) void k_heavy(
    const float* __restrict__ fg, const float* __restrict__ bg,
    const float* __restrict__ bgT, const float* __restrict__ k1d,
    float* __restrict__ acln) {
  __shared__ _Float16 s_cs[TP * CC];
  __shared__ float s_fg[TP * PL];
  __shared__ float s_red[8];
  __shared__ float s_wwd[TP];
  __shared__ float s_den[TP];

  const int tid = threadIdx.x;
  const int X0 = blockIdx.x * TP;
  const int Y = blockIdx.y;
  const int b = blockIdx.z;

  for (int i = tid; i < TP * PL; i += 256) {
    int p = i / PL, r = i - p * PL;
    int kk = r >> 6, ch = r & 63;
    int ki = kk / 3, kj = kk - 3 * ki;
    int hy = Y + ki - 1, wx = X0 + p + kj - 1;
    float v = 0.f;
    if (hy >= 0 && hy < HH && wx >= 0 && wx < WW)
      v = fg[(((size_t)b * HH + hy) * WW + wx) * DD + ch];
    s_fg[i] = v;
  }
  __syncthreads();
  {
    int p = tid >> 5, lane = tid & 31;
    float a = 0.f;
    for (int r = lane; r < PL; r += 32) {
      float v = s_fg[p * PL + r];
      a = fmaf(v, v, a);
    }
#pragma unroll
    for (int m = 16; m; m >>= 1) a += __shfl_xor(a, m, 64);
    if (lane == 0) s_wwd[p] = a;
  }
  __syncthreads();

  const float* bgTb = bgT + (size_t)b * DD * HH * WW;
  for (int sw = 0; sw < 4; ++sw) {
    const int cb = sw * 256 + tid;
    float acc[TP][4];
#pragma unroll
    for (int p = 0; p < TP; ++p)
#pragma unroll
      for (int q = 0; q < 4; ++q) acc[p][q] = 0.f;
    int off4[4];
#pragma unroll
    for (int q = 0; q < 4; ++q) {
      int c = cb + q * 1024;
      if (c >= CC) c = CC - 1;
      int ci = c / PH;
      off4[q] = ci * WW + (c - ci * PH);
    }
    for (int ch = 0; ch < DD; ++ch) {
      const float* bgTc = bgTb + (size_t)ch * (HH * WW);
#pragma unroll
      for (int kk = 0; kk < 9; ++kk) {
        const int ki = kk / 3, kj = kk - 3 * (kk / 3);
        float fv[TP];
#pragma unroll
        for (int p = 0; p < TP; ++p) fv[p] = s_fg[p * PL + (kk << 6) + ch];
        float bv[4];
#pragma unroll
        for (int q = 0; q < 4; ++q) bv[q] = bgTc[off4[q] + ki * WW + kj];
#pragma unroll
        for (int p = 0; p < TP; ++p)
#pragma unroll
          for (int q = 0; q < 4; ++q) acc[p][q] = fmaf(fv[p], bv[q], acc[p][q]);
      }
    }
#pragma unroll
    for (int q = 0; q < 4; ++q) {
      int c = cb + q * 1024;
      if (c < CC) {
#pragma unroll
        for (int p = 0; p < TP; ++p) s_cs[p * CC + c] = (_Float16)acc[p][q];
      }
    }
  }
  __syncthreads();

  const float* k1db = k1d + b * CC;
  for (int pos = 0; pos < TP; ++pos) {
    __syncthreads();
    const float wwdp = s_wwd[pos];
    float s1 = 0.f, s2 = 0.f;
    for (int c = tid; c < CC; c += 256) {
      float ds1 = k1db[c] + wwdp - 2.f * (float)s_cs[pos * CC + c];
      s1 += ds1;
      s2 = fmaf(ds1, ds1, s2);
    }
#pragma unroll
    for (int m = 32; m; m >>= 1) {
      s1 += __shfl_xor(s1, m, 64);
      s2 += __shfl_xor(s2, m, 64);
    }
    if ((tid & 63) == 0) {
      int w = tid >> 6;
      s_red[w] = s1;
      s_red[4 + w] = s2;
    }
    __syncthreads();
    float mu = (s_red[0] + s_red[1] + s_red[2] + s_red[3]) * (1.f / CC);
    float ex2 = (s_red[4] + s_red[5] + s_red[6] + s_red[7]) * (1.f / CC);
    float var = fmaxf(ex2 - mu * mu, 1e-12f);
    float rsd = rsqrtf(var);
    float dp = 0.f;
    for (int c = tid; c < CC; c += 256) {
      float ds1 = k1db[c] + wwdp - 2.f * (float)s_cs[pos * CC + c];
      float z = (ds1 - mu) * rsd;
      float wv = expf(-LAM * tanhf(z));
      s_cs[pos * CC + c] = (_Float16)wv;
      dp += wv;
    }
#pragma unroll
    for (int m = 32; m; m >>= 1) dp += __shfl_xor(dp, m, 64);
    __syncthreads();
    if ((tid & 63) == 0) s_red[tid >> 6] = dp;
    __syncthreads();
    if (tid == 0) s_den[pos] = s_red[0] + s_red[1] + s_red[2] + s_red[3];
  }

  const int d = tid & 63;
  const int grp = tid >> 6;
  const int oA = grp, oB = grp + 4;
  const int sA = oA / 3, tA = oA - 3 * sA;
  const int sB = oB / 3, tB = oB - 3 * sB;
  const bool hasC = (grp == 0);
  const int offA = (sA * WW + tA) * DD + d;
  const int offB = (sB * WW + tB) * DD + d;
  const int offC = (2 * WW + 2) * DD + d;
  float aA[TP], aB[TP], aC[TP];
#pragma unroll
  for (int p = 0; p < TP; ++p) { aA[p] = 0.f; aB[p] = 0.f; aC[p] = 0.f; }
  const float* bgb = bg + (size_t)b * HH * WW * DD;
  float* s_wf = s_fg;
  int cj = 0, rowoff = 0;
  for (int c0 = 0; c0 < CC; c0 += 128) {
    const int n = (CC - c0 < 128) ? (CC - c0) : 128;
    __syncthreads();
    for (int i = tid; i < TP * 128; i += 256) {
      int p = i >> 7, cc = i & 127;
      s_wf[i] = (cc < n) ? (float)s_cs[p * CC + c0 + cc] : 0.f;
    }
    __syncthreads();
    for (int cc = 0; cc < n; cc += 2) {
      float2 wv[TP];
#pragma unroll
      for (int p = 0; p < TP; ++p)
        wv[p] = *(const float2*)(s_wf + (p << 7) + cc);
      {
        const float* rp = bgb + (size_t)rowoff * DD;
        float bA = rp[offA], bB = rp[offB], bCv = rp[offC];
#pragma unroll
        for (int p = 0; p < TP; ++p) {
          aA[p] = fmaf(wv[p].x, bA, aA[p]);
          aB[p] = fmaf(wv[p].x, bB, aB[p]);
          if (hasC) aC[p] = fmaf(wv[p].x, bCv, aC[p]);
        }
        ++rowoff;
        if (++cj == PH) { cj = 0; rowoff += 2; }
      }
      {
        const float* rp = bgb + (size_t)rowoff * DD;
        float bA = rp[offA], bB = rp[offB], bCv = rp[offC];
#pragma unroll
        for (int p = 0; p < TP; ++p) {
          aA[p] = fmaf(wv[p].y, bA, aA[p]);
          aB[p] = fmaf(wv[p].y, bB, aB[p]);
          if (hasC) aC[p] = fmaf(wv[p].y, bCv, aC[p]);
        }
        ++rowoff;
        if (++cj == PH) { cj = 0; rowoff += 2; }
      }
    }
  }
  __syncthreads();
#pragma unroll
  for (int p = 0; p < TP; ++p) {
    const float inv = 1.f / (9.f * s_den[p]);
    float* dst = acln + ((((size_t)b * HH + Y) * WW + (X0 + p)) * 9) * 64;
    dst[oA * 64 + d] = aA[p] * inv;
    dst[oB * 64 + d] = aB[p] * inv;
    if (hasC) dst[512 + d] = aC[p] * inv;
  }
}

__global__ __launch_bounds__(256) void k_final(
    const float* __restrict__ bg_in, const float* __restrict__ mask,
    const float* __restrict__ bg, const float* __restrict__ acln,
    const float* __restrict__ Wml, const float* __restrict__ bml,
    float* __restrict__ out) {
  __shared__ float s_con[4 * 128];
  const int tid = threadIdx.x;
  const int posg = blockIdx.x * 4;
  for (int i = tid; i < 4 * 128; i += 256) {
    int p = i >> 7, c = i & 127;
    int pos = posg + p;
    float v;
    if (c < 64) {
      v = bg_in[(size_t)pos * DD + c];
    } else {
      int cc = c - 64;
      int bwx = pos & 4095, bb = pos >> 12;
      int y = bwx >> 6, x = bwx & 63;
      float a = 0.f;
#pragma unroll
      for (int s = 0; s < 3; ++s) {
        int yy = y + 1 - s;
        if (yy < 0 || yy >= HH) continue;
#pragma unroll
        for (int t = 0; t < 3; ++t) {
          int xx = x + 1 - t;
          if (xx < 0 || xx >= WW) continue;
          a += acln[((((size_t)bb * HH + yy) * WW + xx) * 9 + (s * 3 + t)) * 64 + cc];
        }
      }
      float m0 = mask[(size_t)pos * DD];
      v = bg[(size_t)pos * DD + cc] + a * (1.f - m0);
    }
    s_con[i] = v;
  }
  __syncthreads();
  const int o = tid & 63, p = tid >> 6;
  float sum = bml[o];
  const float* cp = s_con + (p << 7);
#pragma unroll 8
  for (int c = 0; c < 128; ++c) sum = fmaf(cp[c], Wml[c * 64 + o], sum);
  out[(size_t)(posg + p) * 64 + o] = (sum > 0.f) ? sum : expm1f(sum);
}

// =============================== launch ===============================
extern "C" void kernel_launch(void* const* d_in, const int* in_sizes, int n_in,
                              void* d_out, int out_size, void* d_ws, size_t ws_size,
                              hipStream_t stream) {
  const float* bg_in = (const float*)d_in[0];
  const float* fg_in = (const float*)d_in[1];
  const float* mask = (const float*)d_in[2];
  const float* Wml = (const float*)d_in[3];
  const float* bml = (const float*)d_in[4];
  float* out = (float*)d_out;

  if (ws_size >= REQ_FAST) {
    char* w8 = (char*)d_ws;
    f16* fgp = (f16*)(w8 + 2097152);
    f16* bgf = (f16*)(w8 + 3212288);
    f16* P1T = (f16*)(w8 + 4310016);
    f16* CS = (f16*)(w8 + 14468096);
    f16* N2 = (f16*)(w8 + 79479808);
    float* k1d = (float*)(w8 + 89965568);
    float* sden = (float*)(w8 + 89997312);

    const int NPREP =
        BB * 4288 * 64 + BB * 4356 * 64 + BB * PLP * CCP + BB * CC;
    k_preall<<<dim3((NPREP + 255) / 256), dim3(256), 0, stream>>>(
        bg_in, fg_in, mask, bgf, fgp, P1T, k1d);
    k_gemm1<<<dim3(CCP / 128, 32, 2), dim3(512), 0, stream>>>(fgp, bgf, CS);
    k_stats<<<dim3(4096, 2), dim3(256), 0, stream>>>(CS, k1d, sden);
    k_gemm2<<<dim3(640), dim3(512), 0, stream>>>(CS, P1T, N2, sden);
    k_final2<<<dim3(2048), dim3(256), 0, stream>>>(bg_in, mask, N2, Wml, bml, out);
  } else {
    float* ws = (float*)d_ws;
    float* bg = ws + WS_BG;
    float* bgT = ws + WS_BGT;
    float* k1d = ws + WS_K1D;
    float* acln = ws + WS_ACLN;
    k_prep<<<dim3(2048), dim3(256), 0, stream>>>(bg_in, mask, bg, bgT);
    k_k1d<<<dim3((BB * CC + 255) / 256), dim3(256), 0, stream>>>(bg, k1d);
    k_heavy<<<dim3(8, 64, 2), dim3(256), 0, stream>>>(fg_in, bg, bgT, k1d, acln);
    k_final<<<dim3(2048), dim3(256), 0, stream>>>(bg_in, mask, bg, acln, Wml, bml, out);
  }
}

// Round 11
// 164.621 us; speedup vs baseline: 1.4373x; 1.2503x over previous
//
#include <hip/hip_runtime.h>
#include <hip/hip_fp16.h>
#include <math.h>

// Problem constants
#define BB 2
#define HH 64
#define WW 64
#define DD 64
#define PH 62          // (H-K)/stride+1
#define CC 3844        // PH*PH
#define CCP 3968       // CC padded to mult of 128
#define PL 576         // K*K*D
#define PLP 640        // PL padded to mult of 128
#define TP 8
#define LAM 10.0f

typedef _Float16 f16;
typedef __attribute__((ext_vector_type(8))) _Float16 half8;
typedef __attribute__((ext_vector_type(4))) float f32x4;

// ======================= FAST PATH (MFMA) =======================
// ws layout (bytes):
//  s2   f32 [2][4096]           @ 0           32,768      (per-pixel masked |bg|^2)
//  (rest of first 2MB unused; kept so fallback layout stays valid)
//  fgp  f16 [2][4356][64]       @ 2,097,152   1,115,136   (66x66 padded fg image)
//  bgf  f16 [2][4288][64]       @ 3,212,288   1,097,728   (bg pixels + zero page)
//  P1T  f16 [2][640][3968]      @ 4,310,016   10,158,080
//  CS   f16 [2][4096][3968]     @ 14,468,096  65,011,712
//  N2   f16 [2][4096][640]      @ 79,479,808  10,485,760
//  k1d  f32 [2][3968]           @ 89,965,568  31,744
//  sden f32 [2][4096]           @ 89,997,312  32,768
#define REQ_FAST 90030080ULL

__device__ __forceinline__ void gld16(const void* g, void* l) {
  __builtin_amdgcn_global_load_lds((const __attribute__((address_space(1))) void*)g,
                                   (__attribute__((address_space(3))) void*)l, 16, 0, 0);
}

// prep A: bgf (masked f16 + zero page), fgp (padded fg f16),
// s2[b][pix] = mask^2 * sum_ch bg_in^2  (16 lanes per pixel, float4 + shfl).
__global__ __launch_bounds__(256) void k_prepA(
    const float* __restrict__ bg_in, const float* __restrict__ fg,
    const float* __restrict__ mask, f16* __restrict__ bgf,
    f16* __restrict__ fgp, float* __restrict__ s2) {
  const int NBG = BB * 4288 * 64;
  const int NFG = BB * 4356 * 64;
  int idx = blockIdx.x * 256 + threadIdx.x;
  if (idx < NBG) {
    int ch = idx & 63;
    int pix = (idx >> 6) % 4288;
    int b = idx / (4288 * 64);
    f16 v = (f16)0.f;
    if (pix < 4096) {
      size_t src = ((size_t)b * 4096 + pix) * 64 + ch;
      v = (f16)(bg_in[src] * mask[((size_t)b * 4096 + pix) * 64]);
    }
    bgf[idx] = v;
  } else if (idx < NBG + NFG) {
    int i2 = idx - NBG;
    int ch = i2 & 63;
    int pix = (i2 >> 6) % 4356;
    int b = i2 / (4356 * 64);
    int yy = pix / 66, xx = pix - 66 * yy;
    float v = 0.f;
    if (yy >= 1 && yy <= 64 && xx >= 1 && xx <= 64)
      v = fg[(((size_t)b * 64 + (yy - 1)) * 64 + (xx - 1)) * 64 + ch];
    fgp[i2] = (f16)v;
  } else {
    int i3 = idx - (NBG + NFG);           // [0, BB*4096*16)
    int q = i3 & 15;
    int pix = (i3 >> 4) & 4095;
    int b = i3 >> 16;                     // 4096*16 = 65536
    float4 v = ((const float4*)(bg_in + ((size_t)b * 4096 + pix) * 64))[q];
    float a = v.x * v.x + v.y * v.y + v.z * v.z + v.w * v.w;
    a += __shfl_xor(a, 1, 64);
    a += __shfl_xor(a, 2, 64);
    a += __shfl_xor(a, 4, 64);
    a += __shfl_xor(a, 8, 64);
    if (q == 0) {
      float m = mask[((size_t)b * 4096 + pix) * 64];
      s2[b * 4096 + pix] = m * m * a;
    }
  }
}

// prep B: k1d[c] = sum of 9 s2 taps; P1T built by LDS-transpose of contiguous
// bgf pixel runs (fixed (kk,ci) -> 62 contiguous pixels). Pad cols zeroed.
__global__ __launch_bounds__(256) void k_prepB(
    const f16* __restrict__ bgf, const float* __restrict__ s2,
    f16* __restrict__ P1T, float* __restrict__ k1d) {
  __shared__ f16 st[62 * 66];   // +66 pad: transpose read <=2-way bank alias
  const int NB1 = 31;           // ceil(BB*CC/256)
  if (blockIdx.x < NB1) {
    int idx = blockIdx.x * 256 + threadIdx.x;
    if (idx < BB * CC) {
      int b = idx / CC, c = idx - b * CC;
      int ci = c / PH, cj = c - ci * PH;
      float s = 0.f;
#pragma unroll
      for (int ki = 0; ki < 3; ++ki)
#pragma unroll
        for (int kj = 0; kj < 3; ++kj)
          s += s2[b * 4096 + (ci + ki) * 64 + cj + kj];
      k1d[(size_t)b * CCP + c] = s;
    }
    return;
  }
  int pb = blockIdx.x - NB1;    // [0, 63*9*2)
  int ci = pb % 63;
  int rest = pb / 63;
  int kk = rest % 9;
  int b = rest / 9;
  int ki = kk / 3, kj = kk - 3 * ki;
  f16* P1Tb = P1T + (size_t)b * PLP * CCP;
  if (ci == 62) {               // zero pad cols c in [CC, CCP) for rows of this kk
    for (int i = threadIdx.x; i < 64 * 124; i += 256) {
      int ch = i / 124, cc = i - ch * 124;
      P1Tb[(size_t)(kk * 64 + ch) * CCP + CC + cc] = (f16)0.f;
    }
    return;
  }
  // load 62 contiguous pixels x 64 ch (contiguous 7936B), transpose via LDS
  const f16* src = bgf + (size_t)b * (4288 * 64) + (size_t)((ci + ki) * 64 + kj) * 64;
  for (int i = threadIdx.x; i < 496; i += 256) {  // 496 = 62*64/8 half8s
    half8 v = ((const half8*)src)[i];
    int p = i >> 3, ch0 = (i & 7) * 8;
#pragma unroll
    for (int j = 0; j < 8; ++j) st[p * 66 + ch0 + j] = v[j];
  }
  __syncthreads();
  for (int i = threadIdx.x; i < 64 * 62; i += 256) {
    int ch = i / 62, cj = i - ch * 62;
    P1Tb[(size_t)(kk * 64 + ch) * CCP + ci * 62 + cj] = st[cj * 66 + ch];
  }
}

// GEMM1: CS[pos][c] = dot(fg patch pos, bg patch c). A,B staged directly from
// padded f16 images (BK=64 == one (ki,kj) tap). 128x128 tile, 8 waves (2x4,
// wave tile 64x32), 512 threads, dbuf LDS 64 KB -> 2 blocks/CU = 16 waves/CU.
__global__ __launch_bounds__(512) void k_gemm1(
    const f16* __restrict__ fgp, const f16* __restrict__ bgf,
    f16* __restrict__ CS) {
  __shared__ f16 tA[2][128 * 64];
  __shared__ f16 tB[2][128 * 64];
  const int tid = threadIdx.x;
  const int l = tid & 63, w = tid >> 6;  // w in [0,8)
  const int b = blockIdx.z;
  const int m0 = blockIdx.y * 128, n0 = blockIdx.x * 128;
  const f16* fgB = fgp + (size_t)b * (4356 * 64);
  const f16* bgB = bgf + (size_t)b * (4288 * 64);

  int pixA[2], chSA[2], aCh[2];
#pragma unroll
  for (int i = 0; i < 2; ++i) {
    aCh[i] = w * 2 + i;
    int li = aCh[i] * 64 + l;
    int r = li >> 3;
    int j = (li & 7) ^ (r & 7);
    chSA[i] = j * 8;
    int pos = m0 + r;
    pixA[i] = (pos >> 6) * 66 + (pos & 63);
  }
  int pixB[2], chSB[2], bCh[2];
#pragma unroll
  for (int i = 0; i < 2; ++i) {
    bCh[i] = w * 2 + i;
    int li = bCh[i] * 64 + l;
    int r = li >> 3;
    int j = (li & 7) ^ (r & 7);
    chSB[i] = j * 8;
    int c = n0 + r;
    if (c < CC) {
      int ci = c / 62;
      pixB[i] = ci * 64 + (c - 62 * ci);
    } else {
      pixB[i] = 4096;  // zero page
    }
  }

  const int wm = (w >> 2) * 64, wn = (w & 3) * 32;
  const int lr = l & 15, lk = l >> 4;
  const int xr = (lr & 7) << 4;

  f32x4 acc[4][2];
#pragma unroll
  for (int mi = 0; mi < 4; ++mi)
#pragma unroll
    for (int ni = 0; ni < 2; ++ni) acc[mi][ni] = (f32x4){0.f, 0.f, 0.f, 0.f};

#pragma unroll
  for (int i = 0; i < 2; ++i) {
    gld16(fgB + (size_t)pixA[i] * 64 + chSA[i], (char*)tA[0] + aCh[i] * 1024);
    gld16(bgB + (size_t)pixB[i] * 64 + chSB[i], (char*)tB[0] + bCh[i] * 1024);
  }
  asm volatile("s_waitcnt vmcnt(0)" ::: "memory");
  __syncthreads();

#pragma unroll 1
  for (int t = 0; t < 9; ++t) {
    const int cur = t & 1;
    if (t + 1 < 9) {
      const int tn = t + 1;
      const int ki = tn / 3, kj = tn - 3 * ki;
      const int offA = ki * 66 + kj, offB = ki * 64 + kj;
#pragma unroll
      for (int i = 0; i < 2; ++i) {
        gld16(fgB + (size_t)(pixA[i] + offA) * 64 + chSA[i],
              (char*)tA[cur ^ 1] + aCh[i] * 1024);
        gld16(bgB + (size_t)(pixB[i] + offB) * 64 + chSB[i],
              (char*)tB[cur ^ 1] + bCh[i] * 1024);
      }
    }
#pragma unroll
    for (int kk = 0; kk < 2; ++kk) {
      half8 av[4], bv[2];
      const int cb = lk * 16 + kk * 64;
#pragma unroll
      for (int mi = 0; mi < 4; ++mi) {
        int r = wm + mi * 16 + lr;
        av[mi] = *(const half8*)((const char*)tA[cur] + r * 128 + (cb ^ xr));
      }
#pragma unroll
      for (int ni = 0; ni < 2; ++ni) {
        int r = wn + ni * 16 + lr;
        bv[ni] = *(const half8*)((const char*)tB[cur] + r * 128 + (cb ^ xr));
      }
#pragma unroll
      for (int mi = 0; mi < 4; ++mi)
#pragma unroll
        for (int ni = 0; ni < 2; ++ni)
          acc[mi][ni] = __builtin_amdgcn_mfma_f32_16x16x32_f16(
              av[mi], bv[ni], acc[mi][ni], 0, 0, 0);
    }
    asm volatile("s_waitcnt vmcnt(0)" ::: "memory");
    __syncthreads();
  }

  CS += (size_t)b * 4096 * CCP;
#pragma unroll
  for (int mi = 0; mi < 4; ++mi) {
#pragma unroll
    for (int q = 0; q < 4; ++q) {
      int m = m0 + wm + mi * 16 + lk * 4 + q;
#pragma unroll
      for (int ni = 0; ni < 2; ++ni) {
        int n = n0 + wn + ni * 16 + lr;
        CS[(size_t)m * CCP + n] = (f16)acc[mi][ni][q];
      }
    }
  }
}

// GEMM2 (R8 known-good form): N2[pos][r] = sden[pos]*sum_c CA[pos][c]*P1T[r][c].
// NT GEMM, 64x128 tile, BK=64, 8 waves (2x4, wave tile 32x32), 512 threads,
// dbuf LDS 48 KB -> 3 blocks/CU = 24 waves/CU. 640 blocks, bijective XCD
// swizzle. NOTE: counted-vmcnt pipelines tried twice (R5, R9) — both regressed
// by trading occupancy for depth. 2-phase + max TLP wins on this structure.
__global__ __launch_bounds__(512) void k_gemm2(
    const f16* __restrict__ A, const f16* __restrict__ B, f16* __restrict__ C,
    const float* __restrict__ sden) {
  __shared__ f16 tA[2][64 * 64];
  __shared__ f16 tB[2][128 * 64];
  const int tid = threadIdx.x;
  const int l = tid & 63, w = tid >> 6;  // w in [0,8)
  const int p = blockIdx.x;
  const int L = (p & 7) * 80 + (p >> 3);
  const int b = L / 320;
  const int rL = L - b * 320;
  const int mt = rL / 5, nt = rL - mt * 5;
  const int m0 = mt * 64, n0 = nt * 128;
  A += (size_t)b * 4096 * CCP;
  B += (size_t)b * PLP * CCP;
  C += (size_t)b * 4096 * PLP;
  const float* sd = sden + (size_t)b * 4096;

  size_t aOff;
  {
    int li = w * 64 + l;
    int r = li >> 3;
    int j = (li & 7) ^ (r & 7);
    aOff = (size_t)(m0 + r) * CCP + j * 8;
  }
  size_t bOff[2];
  int bCh[2];
#pragma unroll
  for (int i = 0; i < 2; ++i) {
    bCh[i] = w * 2 + i;
    int li = bCh[i] * 64 + l;
    int r = li >> 3;
    int j = (li & 7) ^ (r & 7);
    bOff[i] = (size_t)(n0 + r) * CCP + j * 8;
  }

  const int wm = (w >> 2) * 32, wn = (w & 3) * 32;
  const int lr = l & 15, lk = l >> 4;
  const int xr = (lr & 7) << 4;

  f32x4 acc[2][2];
#pragma unroll
  for (int mi = 0; mi < 2; ++mi)
#pragma unroll
    for (int ni = 0; ni < 2; ++ni) acc[mi][ni] = (f32x4){0.f, 0.f, 0.f, 0.f};

  auto STAGE = [&](int buf, int k0) {
    gld16(A + aOff + k0, (char*)tA[buf] + w * 1024);
#pragma unroll
    for (int i = 0; i < 2; ++i)
      gld16(B + bOff[i] + k0, (char*)tB[buf] + bCh[i] * 1024);
  };

  const int NT = CCP / 64;  // 62
  STAGE(0, 0);
  asm volatile("s_waitcnt vmcnt(0)" ::: "memory");
  __syncthreads();

#pragma unroll 1
  for (int t = 0; t < NT; ++t) {
    const int cur = t & 1;
    if (t + 1 < NT) STAGE(cur ^ 1, (t + 1) * 64);
#pragma unroll
    for (int kk = 0; kk < 2; ++kk) {
      half8 av[2], bv[2];
      const int cb = lk * 16 + kk * 64;
#pragma unroll
      for (int mi = 0; mi < 2; ++mi) {
        int r = wm + mi * 16 + lr;
        av[mi] = *(const half8*)((const char*)tA[cur] + r * 128 + (cb ^ xr));
      }
#pragma unroll
      for (int ni = 0; ni < 2; ++ni) {
        int r = wn + ni * 16 + lr;
        bv[ni] = *(const half8*)((const char*)tB[cur] + r * 128 + (cb ^ xr));
      }
#pragma unroll
      for (int mi = 0; mi < 2; ++mi)
#pragma unroll
        for (int ni = 0; ni < 2; ++ni)
          acc[mi][ni] = __builtin_amdgcn_mfma_f32_16x16x32_f16(
              av[mi], bv[ni], acc[mi][ni], 0, 0, 0);
    }
    asm volatile("s_waitcnt vmcnt(0)" ::: "memory");
    __syncthreads();
  }

#pragma unroll
  for (int mi = 0; mi < 2; ++mi) {
#pragma unroll
    for (int q = 0; q < 4; ++q) {
      int m = m0 + wm + mi * 16 + lk * 4 + q;
      float sc = sd[m];
#pragma unroll
      for (int ni = 0; ni < 2; ++ni) {
        int n = n0 + wn + ni * 16 + lr;
        C[(size_t)m * PLP + n] = (f16)(acc[mi][ni][q] * sc);
      }
    }
  }
}

// one-pass stats, fully vectorized: thread t owns 16 contiguous cols.
__global__ __launch_bounds__(256) void k_stats(f16* __restrict__ CS,
                                               const float* __restrict__ k1d,
                                               float* __restrict__ sden) {
  __shared__ float red[8];
  const int tid = threadIdx.x;
  const int row = blockIdx.x, b = blockIdx.y;
  f16* cs = CS + ((size_t)b * 4096 + row) * CCP;
  const float* kd = k1d + (size_t)b * CCP;
  const int base = tid * 16;
  const bool act = base < CCP;  // t < 248

  float tv[16];
  float s1 = 0.f, s2 = 0.f;
  if (act) {
    half8 v0 = ((const half8*)(cs + base))[0];
    half8 v1 = ((const half8*)(cs + base))[1];
    float kv[16];
    *(float4*)(kv + 0) = ((const float4*)(kd + base))[0];
    *(float4*)(kv + 4) = ((const float4*)(kd + base))[1];
    *(float4*)(kv + 8) = ((const float4*)(kd + base))[2];
    *(float4*)(kv + 12) = ((const float4*)(kd + base))[3];
#pragma unroll
    for (int i = 0; i < 16; ++i) {
      float cval = (float)(i < 8 ? v0[i] : v1[i - 8]);
      float t = (base + i < CC) ? (kv[i] - 2.f * cval) : 0.f;
      tv[i] = t;
      s1 += t;
      s2 = fmaf(t, t, s2);
    }
  } else {
#pragma unroll
    for (int i = 0; i < 16; ++i) tv[i] = 0.f;
  }
#pragma unroll
  for (int m = 32; m; m >>= 1) {
    s1 += __shfl_xor(s1, m, 64);
    s2 += __shfl_xor(s2, m, 64);
  }
  if ((tid & 63) == 0) {
    red[tid >> 6] = s1;
    red[4 + (tid >> 6)] = s2;
  }
  __syncthreads();
  float mu = (red[0] + red[1] + red[2] + red[3]) * (1.f / CC);
  float ex2 = (red[4] + red[5] + red[6] + red[7]) * (1.f / CC);
  float var = fmaxf(ex2 - mu * mu, 1e-12f);
  float rsd = rsqrtf(var);
  __syncthreads();

  float den = 0.f;
  if (act) {
    half8 w0, w1;
#pragma unroll
    for (int i = 0; i < 16; ++i) {
      float wv = 0.f;
      if (base + i < CC) {
        float z = (tv[i] - mu) * rsd;
        float e2z = __expf(2.f * z);
        float th = 1.f - 2.f / (e2z + 1.f);  // tanh(z)
        wv = __expf(-LAM * th);
        den += wv;
      }
      if (i < 8) w0[i] = (f16)wv; else w1[i - 8] = (f16)wv;
    }
    ((half8*)(cs + base))[0] = w0;
    ((half8*)(cs + base))[1] = w1;
  }
#pragma unroll
  for (int m = 32; m; m >>= 1) den += __shfl_xor(den, m, 64);
  if ((tid & 63) == 0) red[tid >> 6] = den;
  __syncthreads();
  if (tid == 0)
    sden[(size_t)b * 4096 + row] = 1.f / (9.f * (red[0] + red[1] + red[2] + red[3]));
}

// gather 9-neighbor numerators (already normalized), mask-gate, 1x1 conv, ELU
__global__ __launch_bounds__(256) void k_final2(
    const float* __restrict__ bg_in, const float* __restrict__ mask,
    const f16* __restrict__ N2, const float* __restrict__ Wml,
    const float* __restrict__ bml, float* __restrict__ out) {
  __shared__ float s_con[4 * 128];
  const int tid = threadIdx.x;
  const int posg = blockIdx.x * 4;
  for (int i = tid; i < 4 * 128; i += 256) {
    int p = i >> 7, c = i & 127;
    int pos = posg + p;
    float v;
    if (c < 64) {
      v = bg_in[(size_t)pos * DD + c];
    } else {
      int cc = c - 64;
      int bwx = pos & 4095, bb = pos >> 12;
      int y = bwx >> 6, x = bwx & 63;
      float a = 0.f;
#pragma unroll
      for (int s = 0; s < 3; ++s) {
        int yy = y + 1 - s;
        if (yy < 0 || yy >= HH) continue;
#pragma unroll
        for (int t = 0; t < 3; ++t) {
          int xx = x + 1 - t;
          if (xx < 0 || xx >= WW) continue;
          a += (float)N2[((size_t)bb * 4096 + yy * 64 + xx) * PLP + (s * 3 + t) * 64 + cc];
        }
      }
      float m0 = mask[(size_t)pos * DD];
      v = bg_in[(size_t)pos * DD + cc] * m0 + a * (1.f - m0);
    }
    s_con[i] = v;
  }
  __syncthreads();
  const int o = tid & 63, p = tid >> 6;
  float sum = bml[o];
  const float* cp = s_con + (p << 7);
#pragma unroll 8
  for (int c = 0; c < 128; ++c) sum = fmaf(cp[c], Wml[c * 64 + o], sum);
  out[(size_t)(posg + p) * 64 + o] = (sum > 0.f) ? sum : expm1f(sum);
}

// ======================= FALLBACK PATH (round-1, known-good) ==================
#define WS_BG    0
#define WS_BGT   524288
#define WS_K1D   1048576
#define WS_ACLN  1056264

__global__ __launch_bounds__(256) void k_prep(
    const float* __restrict__ bg_in, const float* __restrict__ mask,
    float* __restrict__ bg, float* __restrict__ bgT) {
  int idx = blockIdx.x * 256 + threadIdx.x;
  if (idx >= BB * HH * WW * DD) return;
  int ch = idx & 63, pos = idx >> 6;
  float m = mask[(size_t)pos * DD];
  float v = bg_in[idx] * m;
  bg[idx] = v;
  int x = pos & 63, rest = pos >> 6;
  int y = rest & 63, b = rest >> 6;
  bgT[(((size_t)b * DD + ch) * HH + y) * WW + x] = v;
}

__global__ __launch_bounds__(256) void k_k1d(const float* __restrict__ bg,
                                             float* __restrict__ k1d) {
  int idx = blockIdx.x * 256 + threadIdx.x;
  if (idx >= BB * CC) return;
  int b = idx / CC, c = idx - b * CC;
  int ci = c / PH, cj = c - ci * PH;
  float s = 0.f;
  for (int ki = 0; ki < 3; ++ki)
    for (int kj = 0; kj < 3; ++kj) {
      const float4* p =
          (const float4*)(bg + (((size_t)(b * HH + ci + ki) * WW) + cj + kj) * DD);
#pragma unroll
      for (int q = 0; q < 16; ++q) {
        float4 v = p[q];
        s += v.x * v.x + v.y * v.y + v.z * v.z + v.w * v.w;
      }
    }
  k1d[idx] = s;
}

__global__ __launch_bounds__(256, 2) void k_heavy(
    const float* __restrict__ fg, const float* __restrict__ bg,
    const float* __restrict__ bgT, const float* __restrict__ k1d,
    float* __restrict__ acln) {
  __shared__ _Float16 s_cs[TP * CC];
  __shared__ float s_fg[TP * PL];
  __shared__ float s_red[8];
  __shared__ float s_wwd[TP];
  __shared__ float s_den[TP];

  const int tid = threadIdx.x;
  const int X0 = blockIdx.x * TP;
  const int Y = blockIdx.y;
  const int b = blockIdx.z;

  for (int i = tid; i < TP * PL; i += 256) {
    int p = i / PL, r = i - p * PL;
    int kk = r >> 6, ch = r & 63;
    int ki = kk / 3, kj = kk - 3 * ki;
    int hy = Y + ki - 1, wx = X0 + p + kj - 1;
    float v = 0.f;
    if (hy >= 0 && hy < HH && wx >= 0 && wx < WW)
      v = fg[(((size_t)b * HH + hy) * WW + wx) * DD + ch];
    s_fg[i] = v;
  }
  __syncthreads();
  {
    int p = tid >> 5, lane = tid & 31;
    float a = 0.f;
    for (int r = lane; r < PL; r += 32) {
      float v = s_fg[p * PL + r];
      a = fmaf(v, v, a);
    }
#pragma unroll
    for (int m = 16; m; m >>= 1) a += __shfl_xor(a, m, 64);
    if (lane == 0) s_wwd[p] = a;
  }
  __syncthreads();

  const float* bgTb = bgT + (size_t)b * DD * HH * WW;
  for (int sw = 0; sw < 4; ++sw) {
    const int cb = sw * 256 + tid;
    float acc[TP][4];
#pragma unroll
    for (int p = 0; p < TP; ++p)
#pragma unroll
      for (int q = 0; q < 4; ++q) acc[p][q] = 0.f;
    int off4[4];
#pragma unroll
    for (int q = 0; q < 4; ++q) {
      int c = cb + q * 1024;
      if (c >= CC) c = CC - 1;
      int ci = c / PH;
      off4[q] = ci * WW + (c - ci * PH);
    }
    for (int ch = 0; ch < DD; ++ch) {
      const float* bgTc = bgTb + (size_t)ch * (HH * WW);
#pragma unroll
      for (int kk = 0; kk < 9; ++kk) {
        const int ki = kk / 3, kj = kk - 3 * (kk / 3);
        float fv[TP];
#pragma unroll
        for (int p = 0; p < TP; ++p) fv[p] = s_fg[p * PL + (kk << 6) + ch];
        float bv[4];
#pragma unroll
        for (int q = 0; q < 4; ++q) bv[q] = bgTc[off4[q] + ki * WW + kj];
#pragma unroll
        for (int p = 0; p < TP; ++p)
#pragma unroll
          for (int q = 0; q < 4; ++q) acc[p][q] = fmaf(fv[p], bv[q], acc[p][q]);
      }
    }
#pragma unroll
    for (int q = 0; q < 4; ++q) {
      int c = cb + q * 1024;
      if (c < CC) {
#pragma unroll
        for (int p = 0; p < TP; ++p) s_cs[p * CC + c] = (_Float16)acc[p][q];
      }
    }
  }
  __syncthreads();

  const float* k1db = k1d + b * CC;
  for (int pos = 0; pos < TP; ++pos) {
    __syncthreads();
    const float wwdp = s_wwd[pos];
    float s1 = 0.f, s2 = 0.f;
    for (int c = tid; c < CC; c += 256) {
      float ds1 = k1db[c] + wwdp - 2.f * (float)s_cs[pos * CC + c];
      s1 += ds1;
      s2 = fmaf(ds1, ds1, s2);
    }
#pragma unroll
    for (int m = 32; m; m >>= 1) {
      s1 += __shfl_xor(s1, m, 64);
      s2 += __shfl_xor(s2, m, 64);
    }
    if ((tid & 63) == 0) {
      int w = tid >> 6;
      s_red[w] = s1;
      s_red[4 + w] = s2;
    }
    __syncthreads();
    float mu = (s_red[0] + s_red[1] + s_red[2] + s_red[3]) * (1.f / CC);
    float ex2 = (s_red[4] + s_red[5] + s_red[6] + s_red[7]) * (1.f / CC);
    float var = fmaxf(ex2 - mu * mu, 1e-12f);
    float rsd = rsqrtf(var);
    float dp = 0.f;
    for (int c = tid; c < CC; c += 256) {
      float ds1 = k1db[c] + wwdp - 2.f * (float)s_cs[pos * CC + c];
      float z = (ds1 - mu) * rsd;
      float wv = expf(-LAM * tanhf(z));
      s_cs[pos * CC + c] = (_Float16)wv;
      dp += wv;
    }
#pragma unroll
    for (int m = 32; m; m >>= 1) dp += __shfl_xor(dp, m, 64);
    __syncthreads();
    if ((tid & 63) == 0) s_red[tid >> 6] = dp;
    __syncthreads();
    if (tid == 0) s_den[pos] = s_red[0] + s_red[1] + s_red[2] + s_red[3];
  }

  const int d = tid & 63;
  const int grp = tid >> 6;
  const int oA = grp, oB = grp + 4;
  const int sA = oA / 3, tA = oA - 3 * sA;
  const int sB = oB / 3, tB = oB - 3 * sB;
  const bool hasC = (grp == 0);
  const int offA = (sA * WW + tA) * DD + d;
  const int offB = (sB * WW + tB) * DD + d;
  const int offC = (2 * WW + 2) * DD + d;
  float aA[TP], aB[TP], aC[TP];
#pragma unroll
  for (int p = 0; p < TP; ++p) { aA[p] = 0.f; aB[p] = 0.f; aC[p] = 0.f; }
  const float* bgb = bg + (size_t)b * HH * WW * DD;
  float* s_wf = s_fg;
  int cj = 0, rowoff = 0;
  for (int c0 = 0; c0 < CC; c0 += 128) {
    const int n = (CC - c0 < 128) ? (CC - c0) : 128;
    __syncthreads();
    for (int i = tid; i < TP * 128; i += 256) {
      int p = i >> 7, cc = i & 127;
      s_wf[i] = (cc < n) ? (float)s_cs[p * CC + c0 + cc] : 0.f;
    }
    __syncthreads();
    for (int cc = 0; cc < n; cc += 2) {
      float2 wv[TP];
#pragma unroll
      for (int p = 0; p < TP; ++p)
        wv[p] = *(const float2*)(s_wf + (p << 7) + cc);
      {
        const float* rp = bgb + (size_t)rowoff * DD;
        float bA = rp[offA], bB = rp[offB], bCv = rp[offC];
#pragma unroll
        for (int p = 0; p < TP; ++p) {
          aA[p] = fmaf(wv[p].x, bA, aA[p]);
          aB[p] = fmaf(wv[p].x, bB, aB[p]);
          if (hasC) aC[p] = fmaf(wv[p].x, bCv, aC[p]);
        }
        ++rowoff;
        if (++cj == PH) { cj = 0; rowoff += 2; }
      }
      {
        const float* rp = bgb + (size_t)rowoff * DD;
        float bA = rp[offA], bB = rp[offB], bCv = rp[offC];
#pragma unroll
        for (int p = 0; p < TP; ++p) {
          aA[p] = fmaf(wv[p].y, bA, aA[p]);
          aB[p] = fmaf(wv[p].y, bB, aB[p]);
          if (hasC) aC[p] = fmaf(wv[p].y, bCv, aC[p]);
        }
        ++rowoff;
        if (++cj == PH) { cj = 0; rowoff += 2; }
      }
    }
  }
  __syncthreads();
#pragma unroll
  for (int p = 0; p < TP; ++p) {
    const float inv = 1.f / (9.f * s_den[p]);
    float* dst = acln + ((((size_t)b * HH + Y) * WW + (X0 + p)) * 9) * 64;
    dst[oA * 64 + d] = aA[p] * inv;
    dst[oB * 64 + d] = aB[p] * inv;
    if (hasC) dst[512 + d] = aC[p] * inv;
  }
}

__global__ __launch_bounds__(256) void k_final(
    const float* __restrict__ bg_in, const float* __restrict__ mask,
    const float* __restrict__ bg, const float* __restrict__ acln,
    const float* __restrict__ Wml, const float* __restrict__ bml,
    float* __restrict__ out) {
  __shared__ float s_con[4 * 128];
  const int tid = threadIdx.x;
  const int posg = blockIdx.x * 4;
  for (int i = tid; i < 4 * 128; i += 256) {
    int p = i >> 7, c = i & 127;
    int pos = posg + p;
    float v;
    if (c < 64) {
      v = bg_in[(size_t)pos * DD + c];
    } else {
      int cc = c - 64;
      int bwx = pos & 4095, bb = pos >> 12;
      int y = bwx >> 6, x = bwx & 63;
      float a = 0.f;
#pragma unroll
      for (int s = 0; s < 3; ++s) {
        int yy = y + 1 - s;
        if (yy < 0 || yy >= HH) continue;
#pragma unroll
        for (int t = 0; t < 3; ++t) {
          int xx = x + 1 - t;
          if (xx < 0 || xx >= WW) continue;
          a += acln[((((size_t)bb * HH + yy) * WW + xx) * 9 + (s * 3 + t)) * 64 + cc];
        }
      }
      float m0 = mask[(size_t)pos * DD];
      v = bg[(size_t)pos * DD + cc] + a * (1.f - m0);
    }
    s_con[i] = v;
  }
  __syncthreads();
  const int o = tid & 63, p = tid >> 6;
  float sum = bml[o];
  const float* cp = s_con + (p << 7);
#pragma unroll 8
  for (int c = 0; c < 128; ++c) sum = fmaf(cp[c], Wml[c * 64 + o], sum);
  out[(size_t)(posg + p) * 64 + o] = (sum > 0.f) ? sum : expm1f(sum);
}

// =============================== launch ===============================
extern "C" void kernel_launch(void* const* d_in, const int* in_sizes, int n_in,
                              void* d_out, int out_size, void* d_ws, size_t ws_size,
                              hipStream_t stream) {
  const float* bg_in = (const float*)d_in[0];
  const float* fg_in = (const float*)d_in[1];
  const float* mask = (const float*)d_in[2];
  const float* Wml = (const float*)d_in[3];
  const float* bml = (const float*)d_in[4];
  float* out = (float*)d_out;

  if (ws_size >= REQ_FAST) {
    char* w8 = (char*)d_ws;
    float* s2 = (float*)(w8 + 0);
    f16* fgp = (f16*)(w8 + 2097152);
    f16* bgf = (f16*)(w8 + 3212288);
    f16* P1T = (f16*)(w8 + 4310016);
    f16* CS = (f16*)(w8 + 14468096);
    f16* N2 = (f16*)(w8 + 79479808);
    float* k1d = (float*)(w8 + 89965568);
    float* sden = (float*)(w8 + 89997312);

    const int NA = BB * 4288 * 64 + BB * 4356 * 64 + BB * 4096 * 16;
    k_prepA<<<dim3((NA + 255) / 256), dim3(256), 0, stream>>>(
        bg_in, fg_in, mask, bgf, fgp, s2);
    k_prepB<<<dim3(31 + 63 * 9 * 2), dim3(256), 0, stream>>>(bgf, s2, P1T, k1d);
    k_gemm1<<<dim3(CCP / 128, 32, 2), dim3(512), 0, stream>>>(fgp, bgf, CS);
    k_stats<<<dim3(4096, 2), dim3(256), 0, stream>>>(CS, k1d, sden);
    k_gemm2<<<dim3(640), dim3(512), 0, stream>>>(CS, P1T, N2, sden);
    k_final2<<<dim3(2048), dim3(256), 0, stream>>>(bg_in, mask, N2, Wml, bml, out);
  } else {
    float* ws = (float*)d_ws;
    float* bg = ws + WS_BG;
    float* bgT = ws + WS_BGT;
    float* k1d = ws + WS_K1D;
    float* acln = ws + WS_ACLN;
    k_prep<<<dim3(2048), dim3(256), 0, stream>>>(bg_in, mask, bg, bgT);
    k_k1d<<<dim3((BB * CC + 255) / 256), dim3(256), 0, stream>>>(bg, k1d);
    k_heavy<<<dim3(8, 64, 2), dim3(256), 0, stream>>>(fg_in, bg, bgT, k1d, acln);
    k_final<<<dim3(2048), dim3(256), 0, stream>>>(bg_in, mask, bg, acln, Wml, bml, out);
  }
}